// Round 1
// baseline (2402.236 us; speedup 1.0000x reference)
//
#include <hip/hip_runtime.h>
#include <math.h>

#define T_LEN    480000
#define NB       8
#define NK       157      // chunks per batch
#define CHUNKSZ  4096
#define STRIDESZ 3072
#define NFFT_SZ  1024
#define HOP_SZ   256
#define NFREQ    513
#define NFR      13       // frames per chunk
#define HDIM     256
#define EDIM     128
#define XDIM     641      // NFREQ + EDIM
#define GDIM     768      // 3*HDIM
#define PDIM     1026     // 2*NFREQ
#define FR_STRIDE 1026    // floats per frame slot in spec buffer
#define NFRAMES  (NB*NK*NFR)   // 16328
#define NCHUNKS  (NB*NK)       // 1256

#define TWO_PI_D 6.283185307179586

// ---------------- radix-2 DIT FFT, 1024 pts, data in LDS ----------------
// dir = -1.0f forward, +1.0f inverse (unnormalized)
__device__ __forceinline__ void fft1024(float* re, float* im, int tid, float dir) {
  for (int s = 1; s <= 10; ++s) {
    int m = 1 << s, half = m >> 1;
    #pragma unroll 2
    for (int j = tid; j < 512; j += 256) {
      int grp = j >> (s - 1);
      int p   = j & (half - 1);
      int i1  = grp * m + p;
      int i2  = i1 + half;
      float ang = dir * 6.28318530717958647692f * ((float)p / (float)m);
      float sn, c;
      sincosf(ang, &sn, &c);
      float r2 = re[i2], q2 = im[i2];
      float tr = c * r2 - sn * q2;
      float ti = c * q2 + sn * r2;
      float r1 = re[i1], q1 = im[i1];
      re[i2] = r1 - tr; im[i2] = q1 - ti;
      re[i1] = r1 + tr; im[i1] = q1 + ti;
    }
    __syncthreads();
  }
}

// ---------------- window + 1/wsum tables (recomputed every call) ----------------
__global__ void k_tables(float* __restrict__ win, float* __restrict__ wsinv) {
  int tid = threadIdx.x;
  for (int i = tid; i < NFFT_SZ; i += 256) {
    double w = 0.5 - 0.5 * cos((TWO_PI_D / (double)NFFT_SZ) * (double)i);
    win[i] = (float)w;
  }
  for (int pc = tid; pc < CHUNKSZ; pc += 256) {
    int t1 = min(NFR - 1, pc >> 8);
    int t0 = (pc > NFFT_SZ - 1) ? ((pc - 768) >> 8) : 0;
    float ws = 0.f;
    for (int tt = t0; tt <= t1; ++tt) {
      int n = pc - tt * HOP_SZ;
      double w = 0.5 - 0.5 * cos((TWO_PI_D / (double)NFFT_SZ) * (double)n);
      float wf = (float)w;
      ws += wf * wf;
    }
    wsinv[pc] = 1.0f / fmaxf(ws, 1e-8f);
  }
}

// ---------------- forward STFT: one frame per block ----------------
__global__ void k_stft(const float* __restrict__ audio, const float* __restrict__ win,
                       float* __restrict__ spec) {
  int fr = blockIdx.x;
  int b   = fr / (NK * NFR);
  int rem = fr % (NK * NFR);
  int k = rem / NFR, t = rem % NFR;
  int tid = threadIdx.x;
  __shared__ float xin[NFFT_SZ];
  __shared__ float re[NFFT_SZ], im[NFFT_SZ];
  int start = k * STRIDESZ + t * HOP_SZ;   // position in (virtually) padded signal
  for (int i = tid; i < NFFT_SZ; i += 256) {
    int pos = start + i;
    float v = (pos < T_LEN) ? audio[b * T_LEN + pos] : 0.f;
    xin[i] = v * win[i];
  }
  __syncthreads();
  for (int i = tid; i < NFFT_SZ; i += 256) {
    int rv = (int)(__brev((unsigned)i) >> 22);
    re[i] = xin[rv];
    im[i] = 0.f;
  }
  __syncthreads();
  fft1024(re, im, tid, -1.f);
  float* sp = spec + (size_t)fr * FR_STRIDE;
  for (int f = tid; f < NFREQ; f += 256) {
    sp[2 * f]     = re[f];
    sp[2 * f + 1] = im[f];
  }
}

// ---------------- xg = [mag | emb] @ wx  (one frame per block) ----------------
__global__ void k_xg(const float* __restrict__ spec, const float* __restrict__ emb_table,
                     const int* __restrict__ effect_id, const float* __restrict__ wx,
                     float* __restrict__ xg) {
  int fr = blockIdx.x;
  int tid = threadIdx.x;
  int b = fr / (NK * NFR);
  __shared__ float x[XDIM];
  const float* sp = spec + (size_t)fr * FR_STRIDE;
  for (int f = tid; f < NFREQ; f += 256) {
    float r = sp[2 * f], iv = sp[2 * f + 1];
    x[f] = sqrtf(r * r + iv * iv);
  }
  if (tid < EDIM) {
    int e = effect_id[b];
    x[NFREQ + tid] = emb_table[e * EDIM + tid];
  }
  __syncthreads();
  float a0 = 0.f, a1 = 0.f, a2 = 0.f;
  #pragma unroll 4
  for (int f = 0; f < XDIM; ++f) {
    float xv = x[f];
    const float* wrow = wx + (size_t)f * GDIM;
    a0 += xv * wrow[tid];
    a1 += xv * wrow[tid + 256];
    a2 += xv * wrow[tid + 512];
  }
  float* xo = xg + (size_t)fr * GDIM;
  xo[tid]       = a0;
  xo[tid + 256] = a1;
  xo[tid + 512] = a2;
}

// ---------------- GRU: one chunk per block, sequential over 13 steps ----------------
__global__ void k_gru(const float* __restrict__ xg, const float* __restrict__ wh,
                      const float* __restrict__ bias, float* __restrict__ hs) {
  int cb = blockIdx.x;   // 0..NCHUNKS-1
  int tid = threadIdx.x; // 0..255 == hidden unit
  __shared__ float h[HDIM];
  h[tid] = 0.f;
  __syncthreads();
  for (int t = 0; t < NFR; ++t) {
    float hg0 = bias[tid], hg1 = bias[256 + tid], hg2 = bias[512 + tid];
    #pragma unroll 4
    for (int i = 0; i < HDIM; ++i) {
      float hv = h[i];
      const float* wrow = wh + (size_t)i * GDIM;
      hg0 += hv * wrow[tid];
      hg1 += hv * wrow[tid + 256];
      hg2 += hv * wrow[tid + 512];
    }
    const float* xgt = xg + (size_t)(cb * NFR + t) * GDIM;
    float z = 1.f / (1.f + expf(-(xgt[tid] + hg0)));
    float r = 1.f / (1.f + expf(-(xgt[tid + 256] + hg1)));
    float n = tanhf(xgt[tid + 512] + r * hg2);
    float hn = (1.f - z) * n + z * h[tid];
    __syncthreads();
    h[tid] = hn;
    hs[(size_t)(cb * NFR + t) * HDIM + tid] = hn;
    __syncthreads();
  }
}

// ---------------- projection + FiLM modulation of stored spectrum ----------------
__global__ void k_projmod(const float* __restrict__ hs, const float* __restrict__ pw,
                          const float* __restrict__ pb, float* __restrict__ spec) {
  int fr = blockIdx.x;
  int tid = threadIdx.x;
  __shared__ float h[HDIM];
  __shared__ float gb[PDIM];
  h[tid] = hs[(size_t)fr * HDIM + tid];
  __syncthreads();
  for (int col = tid; col < PDIM; col += 256) {
    float acc = pb[col];
    #pragma unroll 4
    for (int i = 0; i < HDIM; ++i) acc += h[i] * pw[(size_t)i * PDIM + col];
    gb[col] = acc;
  }
  __syncthreads();
  float* sp = spec + (size_t)fr * FR_STRIDE;
  for (int f = tid; f < NFREQ; f += 256) {
    float r = sp[2 * f], iv = sp[2 * f + 1];
    float mag = sqrtf(r * r + iv * iv);
    float mm = gb[f] * mag + gb[NFREQ + f];
    float nr, ni;
    if (mag > 0.f) {
      float s = mm / mag;
      nr = r * s; ni = iv * s;
    } else {
      nr = mm; ni = 0.f;     // angle(0)=0 -> cos=1, sin=0
    }
    sp[2 * f]     = nr;
    sp[2 * f + 1] = ni;
  }
}

// ---------------- inverse FFT + win/wsum scaling; overwrite frame slot with y ----------------
__global__ void k_istft(float* __restrict__ spec, const float* __restrict__ win,
                        const float* __restrict__ wsinv) {
  int fr = blockIdx.x;
  int tid = threadIdx.x;
  int t = fr % NFR;
  __shared__ float sre[NFREQ], sim[NFREQ];
  __shared__ float re[NFFT_SZ], im[NFFT_SZ];
  float* sp = spec + (size_t)fr * FR_STRIDE;
  for (int f = tid; f < NFREQ; f += 256) {
    sre[f] = sp[2 * f];
    float iv = sp[2 * f + 1];
    sim[f] = (f == 0 || f == NFREQ - 1) ? 0.f : iv;  // irfft ignores DC/Nyquist imag
  }
  __syncthreads();
  for (int i = tid; i < NFFT_SZ; i += 256) {
    int src = (int)(__brev((unsigned)i) >> 22);
    float r, iv;
    if (src <= 512) { r = sre[src]; iv = sim[src]; }
    else            { r = sre[NFFT_SZ - src]; iv = -sim[NFFT_SZ - src]; }
    re[i] = r; im[i] = iv;
  }
  __syncthreads();
  fft1024(re, im, tid, +1.f);
  for (int i = tid; i < NFFT_SZ; i += 256) {
    float y = re[i] * (1.0f / (float)NFFT_SZ);
    int pc = t * HOP_SZ + i;
    sp[i] = y * win[i] * wsinv[pc];
  }
}

// ---------------- deterministic gather overlap-add ----------------
__global__ void k_gather(const float* __restrict__ ybuf, float* __restrict__ out) {
  int gid = blockIdx.x * 256 + threadIdx.x;
  if (gid >= NB * T_LEN) return;
  int b = gid / T_LEN, pos = gid % T_LEN;
  float acc = 0.f;
  int k_hi = min(NK - 1, pos / STRIDESZ);
  int k_lo = (pos >= CHUNKSZ) ? ((pos - (CHUNKSZ - 1) + (STRIDESZ - 1)) / STRIDESZ) : 0;
  for (int k = k_lo; k <= k_hi; ++k) {
    int pc = pos - k * STRIDESZ;             // position within chunk, [0,4096)
    int t1 = min(NFR - 1, pc >> 8);
    int t0 = (pc > NFFT_SZ - 1) ? ((pc - 768) >> 8) : 0;
    int frbase = (b * NK + k) * NFR;
    for (int tt = t0; tt <= t1; ++tt) {
      acc += ybuf[(size_t)(frbase + tt) * FR_STRIDE + (pc - tt * HOP_SZ)];
    }
  }
  out[gid] = acc;
}

// ---------------- launch ----------------
extern "C" void kernel_launch(void* const* d_in, const int* in_sizes, int n_in,
                              void* d_out, int out_size, void* d_ws, size_t ws_size,
                              hipStream_t stream) {
  const float* audio     = (const float*)d_in[0];
  const float* emb_table = (const float*)d_in[1];
  const float* gru_wx    = (const float*)d_in[2];
  const float* gru_wh    = (const float*)d_in[3];
  const float* gru_b     = (const float*)d_in[4];
  const float* proj_w    = (const float*)d_in[5];
  const float* proj_b    = (const float*)d_in[6];
  const int*   effect_id = (const int*)d_in[7];
  float* out = (float*)d_out;

  // workspace layout (floats): total 33,477,520 fl = 133.9 MB
  float* ws    = (float*)d_ws;
  float* spec  = ws;                                   // NFRAMES*1026 = 16,752,528
  float* xg    = ws + (size_t)NFRAMES * FR_STRIDE;     // NFRAMES*768  = 12,539,904
  float* hs    = xg + (size_t)NFRAMES * GDIM;          // NFRAMES*256  =  4,179,968
  float* win   = hs + (size_t)NFRAMES * HDIM;          // 1024
  float* wsinv = win + NFFT_SZ;                        // 4096

  k_tables <<<1, 256, 0, stream>>>(win, wsinv);
  k_stft   <<<NFRAMES, 256, 0, stream>>>(audio, win, spec);
  k_xg     <<<NFRAMES, 256, 0, stream>>>(spec, emb_table, effect_id, gru_wx, xg);
  k_gru    <<<NCHUNKS, 256, 0, stream>>>(xg, gru_wh, gru_b, hs);
  k_projmod<<<NFRAMES, 256, 0, stream>>>(hs, proj_w, proj_b, spec);
  k_istft  <<<NFRAMES, 256, 0, stream>>>(spec, win, wsinv);
  k_gather <<<(NB * T_LEN + 255) / 256, 256, 0, stream>>>(spec, out);
}

// Round 2
// 1063.436 us; speedup vs baseline: 2.2589x; 2.2589x over previous
//
#include <hip/hip_runtime.h>
#include <math.h>

#define T_LEN    480000
#define NB       8
#define NK       157      // chunks per batch
#define CHUNKSZ  4096
#define STRIDESZ 3072
#define NFFT_SZ  1024
#define HOP_SZ   256
#define NFREQ    513
#define NFR      13       // frames per chunk
#define HDIM     256
#define EDIM     128
#define XDIM     641      // NFREQ + EDIM
#define GDIM     768      // 3*HDIM
#define PDIM     1026     // 2*NFREQ
#define FR_STRIDE 1026    // floats per frame slot in spec buffer
#define NFRAMES  (NB*NK*NFR)   // 16328
#define NCHUNKS  (NB*NK)       // 1256
#define KCF      2041          // NK*NFR, frames per batch

#define TWO_PI_D 6.283185307179586

// ---------------- radix-2 DIT FFT, 1024 pts, data in LDS, table twiddles ----------------
// dir = -1.0f forward, +1.0f inverse (unnormalized). twc/tws: cos/sin(2*pi*q/1024), q<512.
__device__ __forceinline__ void fft1024(float* re, float* im,
                                        const float* twc, const float* tws,
                                        int tid, float dir) {
  for (int s = 1; s <= 10; ++s) {
    int m = 1 << s, half = m >> 1;
    #pragma unroll 2
    for (int j = tid; j < 512; j += 256) {
      int grp = j >> (s - 1);
      int p   = j & (half - 1);
      int i1  = grp * m + p;
      int i2  = i1 + half;
      int q   = p << (10 - s);
      float c  = twc[q];
      float sn = dir * tws[q];
      float r2 = re[i2], q2 = im[i2];
      float tr = c * r2 - sn * q2;
      float ti = c * q2 + sn * r2;
      float r1 = re[i1], q1 = im[i1];
      re[i2] = r1 - tr; im[i2] = q1 - ti;
      re[i1] = r1 + tr; im[i1] = q1 + ti;
    }
    __syncthreads();
  }
}

// ---------------- window + 1/wsum + twiddle tables (recomputed every call) ----------------
__global__ void k_tables(float* __restrict__ win, float* __restrict__ wsinv,
                         float* __restrict__ twc, float* __restrict__ tws) {
  int tid = threadIdx.x;
  for (int i = tid; i < NFFT_SZ; i += 256) {
    double w = 0.5 - 0.5 * cos((TWO_PI_D / (double)NFFT_SZ) * (double)i);
    win[i] = (float)w;
  }
  for (int i = tid; i < 512; i += 256) {
    double th = (TWO_PI_D / (double)NFFT_SZ) * (double)i;
    twc[i] = (float)cos(th);
    tws[i] = (float)sin(th);
  }
  for (int pc = tid; pc < CHUNKSZ; pc += 256) {
    int t1 = min(NFR - 1, pc >> 8);
    int t0 = (pc > NFFT_SZ - 1) ? ((pc - 768) >> 8) : 0;
    float ws = 0.f;
    for (int tt = t0; tt <= t1; ++tt) {
      int n = pc - tt * HOP_SZ;
      double w = 0.5 - 0.5 * cos((TWO_PI_D / (double)NFFT_SZ) * (double)n);
      float wf = (float)w;
      ws += wf * wf;
    }
    wsinv[pc] = 1.0f / fmaxf(ws, 1e-8f);
  }
}

// ---------------- emb @ wx_emb precompute: embxg[b][col] ----------------
__global__ void k_embxg(const float* __restrict__ emb_table, const int* __restrict__ effect_id,
                        const float* __restrict__ wx, float* __restrict__ embxg) {
  int b = blockIdx.x;
  int tid = threadIdx.x;
  int e_id = effect_id[b];
  const float* ev = emb_table + (size_t)e_id * EDIM;
  #pragma unroll
  for (int j = 0; j < 3; ++j) {
    int col = tid + 256 * j;
    float acc = 0.f;
    #pragma unroll 4
    for (int e = 0; e < EDIM; ++e)
      acc += ev[e] * wx[(size_t)(NFREQ + e) * GDIM + col];
    embxg[(size_t)b * GDIM + col] = acc;
  }
}

// ---------------- forward STFT: one frame per block ----------------
__global__ void k_stft(const float* __restrict__ audio, const float* __restrict__ win,
                       const float* __restrict__ gtwc, const float* __restrict__ gtws,
                       float* __restrict__ spec) {
  int fr = blockIdx.x;
  int b   = fr / (NK * NFR);
  int rem = fr % (NK * NFR);
  int k = rem / NFR, t = rem % NFR;
  int tid = threadIdx.x;
  __shared__ float xin[NFFT_SZ];
  __shared__ float re[NFFT_SZ], im[NFFT_SZ];
  __shared__ float twc[512], tws[512];
  for (int i = tid; i < 512; i += 256) { twc[i] = gtwc[i]; tws[i] = gtws[i]; }
  int start = k * STRIDESZ + t * HOP_SZ;
  for (int i = tid; i < NFFT_SZ; i += 256) {
    int pos = start + i;
    float v = (pos < T_LEN) ? audio[b * T_LEN + pos] : 0.f;
    xin[i] = v * win[i];
  }
  __syncthreads();
  for (int i = tid; i < NFFT_SZ; i += 256) {
    int rv = (int)(__brev((unsigned)i) >> 22);
    re[i] = xin[rv];
    im[i] = 0.f;
  }
  __syncthreads();
  fft1024(re, im, twc, tws, tid, -1.f);
  float* sp = spec + (size_t)fr * FR_STRIDE;
  for (int f = tid; f < NFREQ; f += 256) {
    sp[2 * f]     = re[f];
    sp[2 * f + 1] = im[f];
  }
}

// ---------------- xg = [mag | emb] @ wx, tiled 16 frames/block ----------------
#define XG_MT 16
__global__ __launch_bounds__(256) void k_xg(
    const float* __restrict__ spec, const float* __restrict__ embxg,
    const float* __restrict__ wx, float* __restrict__ xg) {
  int fr0 = blockIdx.x * XG_MT;
  int tid = threadIdx.x;
  __shared__ __align__(16) float xs[XG_MT][520];   // mags, cols 513..519 zero-padded
  for (int m = 0; m < XG_MT; ++m) {
    int fr = fr0 + m;
    if (fr < NFRAMES) {
      const float* sp = spec + (size_t)fr * FR_STRIDE;
      for (int f = tid; f < NFREQ; f += 256) {
        float r = sp[2 * f], iv = sp[2 * f + 1];
        xs[m][f] = sqrtf(r * r + iv * iv);
      }
    } else {
      for (int f = tid; f < NFREQ; f += 256) xs[m][f] = 0.f;
    }
    if (tid < 7) xs[m][NFREQ + tid] = 0.f;
  }
  __syncthreads();
  float acc0[XG_MT], acc1[XG_MT], acc2[XG_MT];
  #pragma unroll
  for (int m = 0; m < XG_MT; ++m) { acc0[m] = 0.f; acc1[m] = 0.f; acc2[m] = 0.f; }
  // K covers mag rows 0..512; kb=512 block multiplies zero-pad against wx rows 513..515 (valid mem)
  for (int kb = 0; kb < 516; kb += 4) {
    const float* w = wx + (size_t)kb * GDIM + tid;
    float wa0 = w[0],        wa1 = w[256],        wa2 = w[512];
    float wb0 = w[GDIM],     wb1 = w[GDIM+256],   wb2 = w[GDIM+512];
    float wc0 = w[2*GDIM],   wc1 = w[2*GDIM+256], wc2 = w[2*GDIM+512];
    float wd0 = w[3*GDIM],   wd1 = w[3*GDIM+256], wd2 = w[3*GDIM+512];
    #pragma unroll
    for (int m = 0; m < XG_MT; ++m) {
      float4 xv = *(const float4*)&xs[m][kb];
      acc0[m] += xv.x * wa0; acc1[m] += xv.x * wa1; acc2[m] += xv.x * wa2;
      acc0[m] += xv.y * wb0; acc1[m] += xv.y * wb1; acc2[m] += xv.y * wb2;
      acc0[m] += xv.z * wc0; acc1[m] += xv.z * wc1; acc2[m] += xv.z * wc2;
      acc0[m] += xv.w * wd0; acc1[m] += xv.w * wd1; acc2[m] += xv.w * wd2;
    }
  }
  for (int m = 0; m < XG_MT; ++m) {
    int fr = fr0 + m;
    if (fr >= NFRAMES) break;
    int b = fr / KCF;
    const float* eb = embxg + (size_t)b * GDIM;
    float* xo = xg + (size_t)fr * GDIM;
    xo[tid]       = acc0[m] + eb[tid];
    xo[tid + 256] = acc1[m] + eb[tid + 256];
    xo[tid + 512] = acc2[m] + eb[tid + 512];
  }
}

// ---------------- GRU: 4 chunks per block, sequential over 13 steps ----------------
#define GRU_CT 4
__global__ __launch_bounds__(256) void k_gru(
    const float* __restrict__ xg, const float* __restrict__ wh,
    const float* __restrict__ bias, float* __restrict__ hs) {
  int c0 = blockIdx.x * GRU_CT;
  int tid = threadIdx.x;
  __shared__ __align__(16) float h[GRU_CT][HDIM];
  #pragma unroll
  for (int c = 0; c < GRU_CT; ++c) h[c][tid] = 0.f;
  float b0 = bias[tid], b1 = bias[256 + tid], b2 = bias[512 + tid];
  __syncthreads();
  for (int t = 0; t < NFR; ++t) {
    float hg0[GRU_CT], hg1[GRU_CT], hg2[GRU_CT];
    #pragma unroll
    for (int c = 0; c < GRU_CT; ++c) { hg0[c] = b0; hg1[c] = b1; hg2[c] = b2; }
    for (int kb = 0; kb < HDIM; kb += 4) {
      const float* w = wh + (size_t)kb * GDIM + tid;
      float wa0 = w[0],      wa1 = w[256],      wa2 = w[512];
      float wb0 = w[GDIM],   wb1 = w[GDIM+256], wb2 = w[GDIM+512];
      float wc0 = w[2*GDIM], wc1 = w[2*GDIM+256], wc2 = w[2*GDIM+512];
      float wd0 = w[3*GDIM], wd1 = w[3*GDIM+256], wd2 = w[3*GDIM+512];
      #pragma unroll
      for (int c = 0; c < GRU_CT; ++c) {
        float4 hv = *(const float4*)&h[c][kb];
        hg0[c] += hv.x * wa0; hg1[c] += hv.x * wa1; hg2[c] += hv.x * wa2;
        hg0[c] += hv.y * wb0; hg1[c] += hv.y * wb1; hg2[c] += hv.y * wb2;
        hg0[c] += hv.z * wc0; hg1[c] += hv.z * wc1; hg2[c] += hv.z * wc2;
        hg0[c] += hv.w * wd0; hg1[c] += hv.w * wd1; hg2[c] += hv.w * wd2;
      }
    }
    float hn[GRU_CT];
    #pragma unroll
    for (int c = 0; c < GRU_CT; ++c) {
      const float* xgt = xg + (size_t)((c0 + c) * NFR + t) * GDIM;
      float z = 1.f / (1.f + expf(-(xgt[tid] + hg0[c])));
      float r = 1.f / (1.f + expf(-(xgt[tid + 256] + hg1[c])));
      float n = tanhf(xgt[tid + 512] + r * hg2[c]);
      hn[c] = (1.f - z) * n + z * h[c][tid];
    }
    __syncthreads();
    #pragma unroll
    for (int c = 0; c < GRU_CT; ++c) {
      h[c][tid] = hn[c];
      hs[(size_t)((c0 + c) * NFR + t) * HDIM + tid] = hn[c];
    }
    __syncthreads();
  }
}

// ---------------- projection + FiLM modulation, tiled 8 frames/block ----------------
#define PJ_MT 8
__global__ __launch_bounds__(256) void k_projmod(
    const float* __restrict__ hs, const float* __restrict__ pw,
    const float* __restrict__ pb, float* __restrict__ spec) {
  int fr0 = blockIdx.x * PJ_MT;
  int tid = threadIdx.x;
  __shared__ __align__(16) float h[PJ_MT][HDIM];     // 8 KB
  __shared__ float gb[PJ_MT][PDIM];                  // 32.8 KB
  #pragma unroll
  for (int m = 0; m < PJ_MT; ++m)
    h[m][tid] = hs[(size_t)(fr0 + m) * HDIM + tid];
  __syncthreads();
  float pb0 = pb[tid], pb1 = pb[tid + 256], pb2 = pb[tid + 512], pb3 = pb[tid + 768];
  float a0[PJ_MT], a1[PJ_MT], a2[PJ_MT], a3[PJ_MT];
  #pragma unroll
  for (int m = 0; m < PJ_MT; ++m) { a0[m] = pb0; a1[m] = pb1; a2[m] = pb2; a3[m] = pb3; }
  for (int kb = 0; kb < HDIM; kb += 4) {
    const float* w = pw + (size_t)kb * PDIM + tid;
    float wa0 = w[0],      wa1 = w[256],      wa2 = w[512],      wa3 = w[768];
    float wb0 = w[PDIM],   wb1 = w[PDIM+256], wb2 = w[PDIM+512], wb3 = w[PDIM+768];
    float wc0 = w[2*PDIM], wc1 = w[2*PDIM+256], wc2 = w[2*PDIM+512], wc3 = w[2*PDIM+768];
    float wd0 = w[3*PDIM], wd1 = w[3*PDIM+256], wd2 = w[3*PDIM+512], wd3 = w[3*PDIM+768];
    #pragma unroll
    for (int m = 0; m < PJ_MT; ++m) {
      float4 hv = *(const float4*)&h[m][kb];
      a0[m] += hv.x * wa0; a1[m] += hv.x * wa1; a2[m] += hv.x * wa2; a3[m] += hv.x * wa3;
      a0[m] += hv.y * wb0; a1[m] += hv.y * wb1; a2[m] += hv.y * wb2; a3[m] += hv.y * wb3;
      a0[m] += hv.z * wc0; a1[m] += hv.z * wc1; a2[m] += hv.z * wc2; a3[m] += hv.z * wc3;
      a0[m] += hv.w * wd0; a1[m] += hv.w * wd1; a2[m] += hv.w * wd2; a3[m] += hv.w * wd3;
    }
  }
  #pragma unroll
  for (int m = 0; m < PJ_MT; ++m) {
    gb[m][tid]       = a0[m];
    gb[m][tid + 256] = a1[m];
    gb[m][tid + 512] = a2[m];
    gb[m][tid + 768] = a3[m];   // max col 1023
  }
  // tail cols 1024,1025 for all 8 frames
  if (tid < 16) {
    int m = tid >> 1, col = 1024 + (tid & 1);
    float a = pb[col];
    for (int k = 0; k < HDIM; ++k) a += h[m][k] * pw[(size_t)k * PDIM + col];
    gb[m][col] = a;
  }
  __syncthreads();
  #pragma unroll 2
  for (int m = 0; m < PJ_MT; ++m) {
    float* sp = spec + (size_t)(fr0 + m) * FR_STRIDE;
    for (int f = tid; f < NFREQ; f += 256) {
      float r = sp[2 * f], iv = sp[2 * f + 1];
      float mag = sqrtf(r * r + iv * iv);
      float mm = gb[m][f] * mag + gb[m][NFREQ + f];
      float nr, ni;
      if (mag > 0.f) {
        float s = mm / mag;
        nr = r * s; ni = iv * s;
      } else {
        nr = mm; ni = 0.f;   // angle(0)=0
      }
      sp[2 * f]     = nr;
      sp[2 * f + 1] = ni;
    }
  }
}

// ---------------- inverse FFT + win/wsum scaling; overwrite frame slot with y ----------------
__global__ void k_istft(float* __restrict__ spec, const float* __restrict__ win,
                        const float* __restrict__ wsinv,
                        const float* __restrict__ gtwc, const float* __restrict__ gtws) {
  int fr = blockIdx.x;
  int tid = threadIdx.x;
  int t = fr % NFR;
  __shared__ float sre[NFREQ], sim[NFREQ];
  __shared__ float re[NFFT_SZ], im[NFFT_SZ];
  __shared__ float twc[512], tws[512];
  for (int i = tid; i < 512; i += 256) { twc[i] = gtwc[i]; tws[i] = gtws[i]; }
  float* sp = spec + (size_t)fr * FR_STRIDE;
  for (int f = tid; f < NFREQ; f += 256) {
    sre[f] = sp[2 * f];
    float iv = sp[2 * f + 1];
    sim[f] = (f == 0 || f == NFREQ - 1) ? 0.f : iv;  // irfft ignores DC/Nyquist imag
  }
  __syncthreads();
  for (int i = tid; i < NFFT_SZ; i += 256) {
    int src = (int)(__brev((unsigned)i) >> 22);
    float r, iv;
    if (src <= 512) { r = sre[src]; iv = sim[src]; }
    else            { r = sre[NFFT_SZ - src]; iv = -sim[NFFT_SZ - src]; }
    re[i] = r; im[i] = iv;
  }
  __syncthreads();
  fft1024(re, im, twc, tws, tid, +1.f);
  for (int i = tid; i < NFFT_SZ; i += 256) {
    float y = re[i] * (1.0f / (float)NFFT_SZ);
    int pc = t * HOP_SZ + i;
    sp[i] = y * win[i] * wsinv[pc];
  }
}

// ---------------- deterministic gather overlap-add ----------------
__global__ void k_gather(const float* __restrict__ ybuf, float* __restrict__ out) {
  int gid = blockIdx.x * 256 + threadIdx.x;
  if (gid >= NB * T_LEN) return;
  int b = gid / T_LEN, pos = gid % T_LEN;
  float acc = 0.f;
  int k_hi = min(NK - 1, pos / STRIDESZ);
  int k_lo = (pos >= CHUNKSZ) ? ((pos - (CHUNKSZ - 1) + (STRIDESZ - 1)) / STRIDESZ) : 0;
  for (int k = k_lo; k <= k_hi; ++k) {
    int pc = pos - k * STRIDESZ;
    int t1 = min(NFR - 1, pc >> 8);
    int t0 = (pc > NFFT_SZ - 1) ? ((pc - 768) >> 8) : 0;
    int frbase = (b * NK + k) * NFR;
    for (int tt = t0; tt <= t1; ++tt) {
      acc += ybuf[(size_t)(frbase + tt) * FR_STRIDE + (pc - tt * HOP_SZ)];
    }
  }
  out[gid] = acc;
}

// ---------------- launch ----------------
extern "C" void kernel_launch(void* const* d_in, const int* in_sizes, int n_in,
                              void* d_out, int out_size, void* d_ws, size_t ws_size,
                              hipStream_t stream) {
  const float* audio     = (const float*)d_in[0];
  const float* emb_table = (const float*)d_in[1];
  const float* gru_wx    = (const float*)d_in[2];
  const float* gru_wh    = (const float*)d_in[3];
  const float* gru_b     = (const float*)d_in[4];
  const float* proj_w    = (const float*)d_in[5];
  const float* proj_b    = (const float*)d_in[6];
  const int*   effect_id = (const int*)d_in[7];
  float* out = (float*)d_out;

  float* ws    = (float*)d_ws;
  float* spec  = ws;                                   // NFRAMES*1026
  float* xg    = ws + (size_t)NFRAMES * FR_STRIDE;     // NFRAMES*768
  float* hs    = xg + (size_t)NFRAMES * GDIM;          // NFRAMES*256
  float* win   = hs + (size_t)NFRAMES * HDIM;          // 1024
  float* wsinv = win + NFFT_SZ;                        // 4096
  float* twc   = wsinv + CHUNKSZ;                      // 512
  float* tws   = twc + 512;                            // 512
  float* embxg = tws + 512;                            // 8*768

  k_tables <<<1, 256, 0, stream>>>(win, wsinv, twc, tws);
  k_embxg  <<<NB, 256, 0, stream>>>(emb_table, effect_id, gru_wx, embxg);
  k_stft   <<<NFRAMES, 256, 0, stream>>>(audio, win, twc, tws, spec);
  k_xg     <<<(NFRAMES + XG_MT - 1) / XG_MT, 256, 0, stream>>>(spec, embxg, gru_wx, xg);
  k_gru    <<<NCHUNKS / GRU_CT, 256, 0, stream>>>(xg, gru_wh, gru_b, hs);
  k_projmod<<<NFRAMES / PJ_MT, 256, 0, stream>>>(hs, proj_w, proj_b, spec);
  k_istft  <<<NFRAMES, 256, 0, stream>>>(spec, win, wsinv, twc, tws);
  k_gather <<<(NB * T_LEN + 255) / 256, 256, 0, stream>>>(spec, out);
}

// Round 3
// 994.924 us; speedup vs baseline: 2.4145x; 1.0689x over previous
//
#include <hip/hip_runtime.h>
#include <math.h>

#define T_LEN    480000
#define NB       8
#define NK       157      // chunks per batch
#define CHUNKSZ  4096
#define STRIDESZ 3072
#define NFFT_SZ  1024
#define HOP_SZ   256
#define NFREQ    513
#define NFR      13       // frames per chunk
#define HDIM     256
#define EDIM     128
#define XDIM     641      // NFREQ + EDIM
#define GDIM     768      // 3*HDIM
#define PDIM     1026     // 2*NFREQ
#define FR_STRIDE 1026    // floats per frame slot in spec buffer
#define NFRAMES  (NB*NK*NFR)   // 16328
#define NCHUNKS  (NB*NK)       // 1256
#define KCF      2041          // NK*NFR, frames per batch

#define TWO_PI_D 6.283185307179586

// ---------------- radix-2 DIT FFT, fused stage pairs (5 syncs), table twiddles ----------------
// dir = -1.0f forward, +1.0f inverse (unnormalized). twc/tws: cos/sin(2*pi*q/1024), q<512.
// Each thread owns the quad {i0, i0+half, i0+2half, i0+3half} and runs stages s and s+1
// in registers -- identical arithmetic to the plain radix-2 loop.
__device__ __forceinline__ void fft1024(float* re, float* im,
                                        const float* twc, const float* tws,
                                        int tid, float dir) {
  #pragma unroll
  for (int s = 1; s <= 9; s += 2) {
    int half = 1 << (s - 1);            // 1,4,16,64,256
    int p   = tid & (half - 1);
    int grp = tid >> (s - 1);
    int i0  = grp * 4 * half + p;
    int i1  = i0 + half;
    int i2  = i0 + 2 * half;
    int i3  = i0 + 3 * half;
    float r0 = re[i0], q0 = im[i0], r1 = re[i1], q1 = im[i1];
    float r2 = re[i2], q2 = im[i2], r3 = re[i3], q3 = im[i3];
    // stage s: (0,1) and (2,3), same twiddle p<<(10-s)
    int qa = p << (10 - s);
    float ca = twc[qa], sa = dir * tws[qa];
    float tr = ca * r1 - sa * q1, ti = ca * q1 + sa * r1;
    float u0r = r0 + tr, u0i = q0 + ti;
    float u1r = r0 - tr, u1i = q0 - ti;
    tr = ca * r3 - sa * q3; ti = ca * q3 + sa * r3;
    float u2r = r2 + tr, u2i = q2 + ti;
    float u3r = r2 - tr, u3i = q2 - ti;
    // stage s+1: (u0,u2) twiddle p<<(9-s); (u1,u3) twiddle (p+half)<<(9-s)
    int qb = p << (9 - s);
    int qc = (p + half) << (9 - s);
    float cb = twc[qb], sb = dir * tws[qb];
    float cc = twc[qc], sc = dir * tws[qc];
    tr = cb * u2r - sb * u2i; ti = cb * u2i + sb * u2r;
    re[i0] = u0r + tr; im[i0] = u0i + ti;
    re[i2] = u0r - tr; im[i2] = u0i - ti;
    tr = cc * u3r - sc * u3i; ti = cc * u3i + sc * u3r;
    re[i1] = u1r + tr; im[i1] = u1i + ti;
    re[i3] = u1r - tr; im[i3] = u1i - ti;
    __syncthreads();
  }
}

// ---------------- window + 1/wsum + twiddle tables (recomputed every call) ----------------
__global__ void k_tables(float* __restrict__ win, float* __restrict__ wsinv,
                         float* __restrict__ twc, float* __restrict__ tws) {
  int tid = threadIdx.x;
  for (int i = tid; i < NFFT_SZ; i += 256) {
    double w = 0.5 - 0.5 * cos((TWO_PI_D / (double)NFFT_SZ) * (double)i);
    win[i] = (float)w;
  }
  for (int i = tid; i < 512; i += 256) {
    double th = (TWO_PI_D / (double)NFFT_SZ) * (double)i;
    twc[i] = (float)cos(th);
    tws[i] = (float)sin(th);
  }
  for (int pc = tid; pc < CHUNKSZ; pc += 256) {
    int t1 = min(NFR - 1, pc >> 8);
    int t0 = (pc > NFFT_SZ - 1) ? ((pc - 768) >> 8) : 0;
    float ws = 0.f;
    for (int tt = t0; tt <= t1; ++tt) {
      int n = pc - tt * HOP_SZ;
      double w = 0.5 - 0.5 * cos((TWO_PI_D / (double)NFFT_SZ) * (double)n);
      float wf = (float)w;
      ws += wf * wf;
    }
    wsinv[pc] = 1.0f / fmaxf(ws, 1e-8f);
  }
}

// ---------------- emb @ wx_emb precompute: embxg[b][col] ----------------
__global__ void k_embxg(const float* __restrict__ emb_table, const int* __restrict__ effect_id,
                        const float* __restrict__ wx, float* __restrict__ embxg) {
  int b = blockIdx.x;
  int tid = threadIdx.x;
  int e_id = effect_id[b];
  const float* ev = emb_table + (size_t)e_id * EDIM;
  #pragma unroll
  for (int j = 0; j < 3; ++j) {
    int col = tid + 256 * j;
    float acc = 0.f;
    #pragma unroll 4
    for (int e = 0; e < EDIM; ++e)
      acc += ev[e] * wx[(size_t)(NFREQ + e) * GDIM + col];
    embxg[(size_t)b * GDIM + col] = acc;
  }
}

// ---------------- forward STFT: one frame per block ----------------
__global__ void k_stft(const float* __restrict__ audio, const float* __restrict__ win,
                       const float* __restrict__ gtwc, const float* __restrict__ gtws,
                       float* __restrict__ spec) {
  int fr = blockIdx.x;
  int b   = fr / (NK * NFR);
  int rem = fr % (NK * NFR);
  int k = rem / NFR, t = rem % NFR;
  int tid = threadIdx.x;
  __shared__ float xin[NFFT_SZ];
  __shared__ float re[NFFT_SZ], im[NFFT_SZ];
  __shared__ float twc[512], tws[512];
  for (int i = tid; i < 512; i += 256) { twc[i] = gtwc[i]; tws[i] = gtws[i]; }
  int start = k * STRIDESZ + t * HOP_SZ;
  for (int i = tid; i < NFFT_SZ; i += 256) {
    int pos = start + i;
    float v = (pos < T_LEN) ? audio[b * T_LEN + pos] : 0.f;
    xin[i] = v * win[i];
  }
  __syncthreads();
  for (int i = tid; i < NFFT_SZ; i += 256) {
    int rv = (int)(__brev((unsigned)i) >> 22);
    re[i] = xin[rv];
    im[i] = 0.f;
  }
  __syncthreads();
  fft1024(re, im, twc, tws, tid, -1.f);
  float* sp = spec + (size_t)fr * FR_STRIDE;
  for (int f = tid; f < NFREQ; f += 256) {
    sp[2 * f]     = re[f];
    sp[2 * f + 1] = im[f];
  }
}

// ---------------- xg = [mag | emb] @ wx, tiled 16 frames/block ----------------
#define XG_MT 16
__global__ __launch_bounds__(256) void k_xg(
    const float* __restrict__ spec, const float* __restrict__ embxg,
    const float* __restrict__ wx, float* __restrict__ xg) {
  int fr0 = blockIdx.x * XG_MT;
  int tid = threadIdx.x;
  __shared__ __align__(16) float xs[XG_MT][520];   // mags, cols 513..519 zero-padded
  for (int m = 0; m < XG_MT; ++m) {
    int fr = fr0 + m;
    if (fr < NFRAMES) {
      const float* sp = spec + (size_t)fr * FR_STRIDE;
      for (int f = tid; f < NFREQ; f += 256) {
        float r = sp[2 * f], iv = sp[2 * f + 1];
        xs[m][f] = sqrtf(r * r + iv * iv);
      }
    } else {
      for (int f = tid; f < NFREQ; f += 256) xs[m][f] = 0.f;
    }
    if (tid < 7) xs[m][NFREQ + tid] = 0.f;
  }
  __syncthreads();
  float acc0[XG_MT], acc1[XG_MT], acc2[XG_MT];
  #pragma unroll
  for (int m = 0; m < XG_MT; ++m) { acc0[m] = 0.f; acc1[m] = 0.f; acc2[m] = 0.f; }
  for (int kb = 0; kb < 516; kb += 4) {
    const float* w = wx + (size_t)kb * GDIM + tid;
    float wa0 = w[0],        wa1 = w[256],        wa2 = w[512];
    float wb0 = w[GDIM],     wb1 = w[GDIM+256],   wb2 = w[GDIM+512];
    float wc0 = w[2*GDIM],   wc1 = w[2*GDIM+256], wc2 = w[2*GDIM+512];
    float wd0 = w[3*GDIM],   wd1 = w[3*GDIM+256], wd2 = w[3*GDIM+512];
    #pragma unroll
    for (int m = 0; m < XG_MT; ++m) {
      float4 xv = *(const float4*)&xs[m][kb];
      acc0[m] += xv.x * wa0; acc1[m] += xv.x * wa1; acc2[m] += xv.x * wa2;
      acc0[m] += xv.y * wb0; acc1[m] += xv.y * wb1; acc2[m] += xv.y * wb2;
      acc0[m] += xv.z * wc0; acc1[m] += xv.z * wc1; acc2[m] += xv.z * wc2;
      acc0[m] += xv.w * wd0; acc1[m] += xv.w * wd1; acc2[m] += xv.w * wd2;
    }
  }
  for (int m = 0; m < XG_MT; ++m) {
    int fr = fr0 + m;
    if (fr >= NFRAMES) break;
    int b = fr / KCF;
    const float* eb = embxg + (size_t)b * GDIM;
    float* xo = xg + (size_t)fr * GDIM;
    xo[tid]       = acc0[m] + eb[tid];
    xo[tid + 256] = acc1[m] + eb[tid + 256];
    xo[tid + 512] = acc2[m] + eb[tid + 512];
  }
}

// ---------------- GRU: 5 chunks per block (252 blocks = 1/CU), prefetched weights ----------------
#define GRU_CT 5
__global__ __launch_bounds__(256) void k_gru(
    const float* __restrict__ xg, const float* __restrict__ wh,
    const float* __restrict__ bias, float* __restrict__ hs) {
  int c0 = blockIdx.x * GRU_CT;
  int tid = threadIdx.x;
  __shared__ __align__(16) float h[GRU_CT][HDIM];
  #pragma unroll
  for (int c = 0; c < GRU_CT; ++c) h[c][tid] = 0.f;
  float b0 = bias[tid], b1 = bias[256 + tid], b2 = bias[512 + tid];
  __syncthreads();
  for (int t = 0; t < NFR; ++t) {
    float hg0[GRU_CT], hg1[GRU_CT], hg2[GRU_CT];
    #pragma unroll
    for (int c = 0; c < GRU_CT; ++c) { hg0[c] = b0; hg1[c] = b1; hg2[c] = b2; }
    // prefetch kb=0 weights
    float wn[12];
    {
      const float* w = wh + tid;
      #pragma unroll
      for (int r = 0; r < 4; ++r) {
        wn[3*r+0] = w[(size_t)r * GDIM];
        wn[3*r+1] = w[(size_t)r * GDIM + 256];
        wn[3*r+2] = w[(size_t)r * GDIM + 512];
      }
    }
    for (int kb = 0; kb < HDIM; kb += 4) {
      float wcur[12];
      #pragma unroll
      for (int i = 0; i < 12; ++i) wcur[i] = wn[i];
      if (kb + 4 < HDIM) {
        const float* w = wh + (size_t)(kb + 4) * GDIM + tid;
        #pragma unroll
        for (int r = 0; r < 4; ++r) {
          wn[3*r+0] = w[(size_t)r * GDIM];
          wn[3*r+1] = w[(size_t)r * GDIM + 256];
          wn[3*r+2] = w[(size_t)r * GDIM + 512];
        }
      }
      #pragma unroll
      for (int c = 0; c < GRU_CT; ++c) {
        float4 hv = *(const float4*)&h[c][kb];
        hg0[c] += hv.x * wcur[0]; hg1[c] += hv.x * wcur[1];  hg2[c] += hv.x * wcur[2];
        hg0[c] += hv.y * wcur[3]; hg1[c] += hv.y * wcur[4];  hg2[c] += hv.y * wcur[5];
        hg0[c] += hv.z * wcur[6]; hg1[c] += hv.z * wcur[7];  hg2[c] += hv.z * wcur[8];
        hg0[c] += hv.w * wcur[9]; hg1[c] += hv.w * wcur[10]; hg2[c] += hv.w * wcur[11];
      }
    }
    float hn[GRU_CT];
    #pragma unroll
    for (int c = 0; c < GRU_CT; ++c) {
      int cb = c0 + c;
      if (cb < NCHUNKS) {
        const float* xgt = xg + (size_t)(cb * NFR + t) * GDIM;
        float z = 1.f / (1.f + expf(-(xgt[tid] + hg0[c])));
        float r = 1.f / (1.f + expf(-(xgt[tid + 256] + hg1[c])));
        float n = tanhf(xgt[tid + 512] + r * hg2[c]);
        hn[c] = (1.f - z) * n + z * h[c][tid];
      } else hn[c] = 0.f;
    }
    __syncthreads();
    #pragma unroll
    for (int c = 0; c < GRU_CT; ++c) {
      h[c][tid] = hn[c];
      int cb = c0 + c;
      if (cb < NCHUNKS)
        hs[(size_t)(cb * NFR + t) * HDIM + tid] = hn[c];
    }
    __syncthreads();
  }
}

// ---------------- projection + FiLM modulation, tiled 8 frames/block ----------------
#define PJ_MT 8
__global__ __launch_bounds__(256) void k_projmod(
    const float* __restrict__ hs, const float* __restrict__ pw,
    const float* __restrict__ pb, float* __restrict__ spec) {
  int fr0 = blockIdx.x * PJ_MT;
  int tid = threadIdx.x;
  __shared__ __align__(16) float h[PJ_MT][HDIM];     // 8 KB
  __shared__ float gb[PJ_MT][PDIM];                  // 32.8 KB
  #pragma unroll
  for (int m = 0; m < PJ_MT; ++m)
    h[m][tid] = hs[(size_t)(fr0 + m) * HDIM + tid];
  __syncthreads();
  float pb0 = pb[tid], pb1 = pb[tid + 256], pb2 = pb[tid + 512], pb3 = pb[tid + 768];
  float a0[PJ_MT], a1[PJ_MT], a2[PJ_MT], a3[PJ_MT];
  #pragma unroll
  for (int m = 0; m < PJ_MT; ++m) { a0[m] = pb0; a1[m] = pb1; a2[m] = pb2; a3[m] = pb3; }
  for (int kb = 0; kb < HDIM; kb += 4) {
    const float* w = pw + (size_t)kb * PDIM + tid;
    float wa0 = w[0],      wa1 = w[256],      wa2 = w[512],      wa3 = w[768];
    float wb0 = w[PDIM],   wb1 = w[PDIM+256], wb2 = w[PDIM+512], wb3 = w[PDIM+768];
    float wc0 = w[2*PDIM], wc1 = w[2*PDIM+256], wc2 = w[2*PDIM+512], wc3 = w[2*PDIM+768];
    float wd0 = w[3*PDIM], wd1 = w[3*PDIM+256], wd2 = w[3*PDIM+512], wd3 = w[3*PDIM+768];
    #pragma unroll
    for (int m = 0; m < PJ_MT; ++m) {
      float4 hv = *(const float4*)&h[m][kb];
      a0[m] += hv.x * wa0; a1[m] += hv.x * wa1; a2[m] += hv.x * wa2; a3[m] += hv.x * wa3;
      a0[m] += hv.y * wb0; a1[m] += hv.y * wb1; a2[m] += hv.y * wb2; a3[m] += hv.y * wb3;
      a0[m] += hv.z * wc0; a1[m] += hv.z * wc1; a2[m] += hv.z * wc2; a3[m] += hv.z * wc3;
      a0[m] += hv.w * wd0; a1[m] += hv.w * wd1; a2[m] += hv.w * wd2; a3[m] += hv.w * wd3;
    }
  }
  #pragma unroll
  for (int m = 0; m < PJ_MT; ++m) {
    gb[m][tid]       = a0[m];
    gb[m][tid + 256] = a1[m];
    gb[m][tid + 512] = a2[m];
    gb[m][tid + 768] = a3[m];   // max col 1023
  }
  if (tid < 16) {
    int m = tid >> 1, col = 1024 + (tid & 1);
    float a = pb[col];
    for (int k = 0; k < HDIM; ++k) a += h[m][k] * pw[(size_t)k * PDIM + col];
    gb[m][col] = a;
  }
  __syncthreads();
  #pragma unroll 2
  for (int m = 0; m < PJ_MT; ++m) {
    float* sp = spec + (size_t)(fr0 + m) * FR_STRIDE;
    for (int f = tid; f < NFREQ; f += 256) {
      float r = sp[2 * f], iv = sp[2 * f + 1];
      float mag = sqrtf(r * r + iv * iv);
      float mm = gb[m][f] * mag + gb[m][NFREQ + f];
      float nr, ni;
      if (mag > 0.f) {
        float s = mm / mag;
        nr = r * s; ni = iv * s;
      } else {
        nr = mm; ni = 0.f;   // angle(0)=0
      }
      sp[2 * f]     = nr;
      sp[2 * f + 1] = ni;
    }
  }
}

// ---------------- inverse FFT + win/wsum scaling; overwrite frame slot with y ----------------
__global__ void k_istft(float* __restrict__ spec, const float* __restrict__ win,
                        const float* __restrict__ wsinv,
                        const float* __restrict__ gtwc, const float* __restrict__ gtws) {
  int fr = blockIdx.x;
  int tid = threadIdx.x;
  int t = fr % NFR;
  __shared__ float sre[NFREQ], sim[NFREQ];
  __shared__ float re[NFFT_SZ], im[NFFT_SZ];
  __shared__ float twc[512], tws[512];
  for (int i = tid; i < 512; i += 256) { twc[i] = gtwc[i]; tws[i] = gtws[i]; }
  float* sp = spec + (size_t)fr * FR_STRIDE;
  for (int f = tid; f < NFREQ; f += 256) {
    sre[f] = sp[2 * f];
    float iv = sp[2 * f + 1];
    sim[f] = (f == 0 || f == NFREQ - 1) ? 0.f : iv;  // irfft ignores DC/Nyquist imag
  }
  __syncthreads();
  for (int i = tid; i < NFFT_SZ; i += 256) {
    int src = (int)(__brev((unsigned)i) >> 22);
    float r, iv;
    if (src <= 512) { r = sre[src]; iv = sim[src]; }
    else            { r = sre[NFFT_SZ - src]; iv = -sim[NFFT_SZ - src]; }
    re[i] = r; im[i] = iv;
  }
  __syncthreads();
  fft1024(re, im, twc, tws, tid, +1.f);
  for (int i = tid; i < NFFT_SZ; i += 256) {
    float y = re[i] * (1.0f / (float)NFFT_SZ);
    int pc = t * HOP_SZ + i;
    sp[i] = y * win[i] * wsinv[pc];
  }
}

// ---------------- deterministic gather overlap-add ----------------
__global__ void k_gather(const float* __restrict__ ybuf, float* __restrict__ out) {
  int gid = blockIdx.x * 256 + threadIdx.x;
  if (gid >= NB * T_LEN) return;
  int b = gid / T_LEN, pos = gid % T_LEN;
  float acc = 0.f;
  int k_hi = min(NK - 1, pos / STRIDESZ);
  int k_lo = (pos >= CHUNKSZ) ? ((pos - (CHUNKSZ - 1) + (STRIDESZ - 1)) / STRIDESZ) : 0;
  for (int k = k_lo; k <= k_hi; ++k) {
    int pc = pos - k * STRIDESZ;
    int t1 = min(NFR - 1, pc >> 8);
    int t0 = (pc > NFFT_SZ - 1) ? ((pc - 768) >> 8) : 0;
    int frbase = (b * NK + k) * NFR;
    for (int tt = t0; tt <= t1; ++tt) {
      acc += ybuf[(size_t)(frbase + tt) * FR_STRIDE + (pc - tt * HOP_SZ)];
    }
  }
  out[gid] = acc;
}

// ---------------- launch ----------------
extern "C" void kernel_launch(void* const* d_in, const int* in_sizes, int n_in,
                              void* d_out, int out_size, void* d_ws, size_t ws_size,
                              hipStream_t stream) {
  const float* audio     = (const float*)d_in[0];
  const float* emb_table = (const float*)d_in[1];
  const float* gru_wx    = (const float*)d_in[2];
  const float* gru_wh    = (const float*)d_in[3];
  const float* gru_b     = (const float*)d_in[4];
  const float* proj_w    = (const float*)d_in[5];
  const float* proj_b    = (const float*)d_in[6];
  const int*   effect_id = (const int*)d_in[7];
  float* out = (float*)d_out;

  float* ws    = (float*)d_ws;
  float* spec  = ws;                                   // NFRAMES*1026
  float* xg    = ws + (size_t)NFRAMES * FR_STRIDE;     // NFRAMES*768
  float* hs    = xg + (size_t)NFRAMES * GDIM;          // NFRAMES*256
  float* win   = hs + (size_t)NFRAMES * HDIM;          // 1024
  float* wsinv = win + NFFT_SZ;                        // 4096
  float* twc   = wsinv + CHUNKSZ;                      // 512
  float* tws   = twc + 512;                            // 512
  float* embxg = tws + 512;                            // 8*768

  k_tables <<<1, 256, 0, stream>>>(win, wsinv, twc, tws);
  k_embxg  <<<NB, 256, 0, stream>>>(emb_table, effect_id, gru_wx, embxg);
  k_stft   <<<NFRAMES, 256, 0, stream>>>(audio, win, twc, tws, spec);
  k_xg     <<<(NFRAMES + XG_MT - 1) / XG_MT, 256, 0, stream>>>(spec, embxg, gru_wx, xg);
  k_gru    <<<(NCHUNKS + GRU_CT - 1) / GRU_CT, 256, 0, stream>>>(xg, gru_wh, gru_b, hs);
  k_projmod<<<NFRAMES / PJ_MT, 256, 0, stream>>>(hs, proj_w, proj_b, spec);
  k_istft  <<<NFRAMES, 256, 0, stream>>>(spec, win, wsinv, twc, tws);
  k_gather <<<(NB * T_LEN + 255) / 256, 256, 0, stream>>>(spec, out);
}

// Round 4
// 887.094 us; speedup vs baseline: 2.7080x; 1.1216x over previous
//
#include <hip/hip_runtime.h>
#include <math.h>

#define T_LEN    480000
#define NB       8
#define NK       157      // chunks per batch
#define CHUNKSZ  4096
#define STRIDESZ 3072
#define NFFT_SZ  1024
#define HOP_SZ   256
#define NFREQ    513
#define NFR      13       // frames per chunk
#define HDIM     256
#define EDIM     128
#define XDIM     641      // NFREQ + EDIM
#define GDIM     768      // 3*HDIM
#define PDIM     1026     // 2*NFREQ
#define FR_STRIDE 1026    // floats per frame slot in spec buffer
#define NFRAMES  (NB*NK*NFR)   // 16328
#define NCHUNKS  (NB*NK)       // 1256
#define KCF      2041          // NK*NFR, frames per batch

#define TWO_PI_D 6.283185307179586

// ---------------- radix-2 DIT FFT, fused stage pairs (5 syncs), table twiddles ----------------
__device__ __forceinline__ void fft1024(float* re, float* im,
                                        const float* twc, const float* tws,
                                        int tid, float dir) {
  #pragma unroll
  for (int s = 1; s <= 9; s += 2) {
    int half = 1 << (s - 1);            // 1,4,16,64,256
    int p   = tid & (half - 1);
    int grp = tid >> (s - 1);
    int i0  = grp * 4 * half + p;
    int i1  = i0 + half;
    int i2  = i0 + 2 * half;
    int i3  = i0 + 3 * half;
    float r0 = re[i0], q0 = im[i0], r1 = re[i1], q1 = im[i1];
    float r2 = re[i2], q2 = im[i2], r3 = re[i3], q3 = im[i3];
    int qa = p << (10 - s);
    float ca = twc[qa], sa = dir * tws[qa];
    float tr = ca * r1 - sa * q1, ti = ca * q1 + sa * r1;
    float u0r = r0 + tr, u0i = q0 + ti;
    float u1r = r0 - tr, u1i = q0 - ti;
    tr = ca * r3 - sa * q3; ti = ca * q3 + sa * r3;
    float u2r = r2 + tr, u2i = q2 + ti;
    float u3r = r2 - tr, u3i = q2 - ti;
    int qb = p << (9 - s);
    int qc = (p + half) << (9 - s);
    float cb = twc[qb], sb = dir * tws[qb];
    float cc = twc[qc], sc = dir * tws[qc];
    tr = cb * u2r - sb * u2i; ti = cb * u2i + sb * u2r;
    re[i0] = u0r + tr; im[i0] = u0i + ti;
    re[i2] = u0r - tr; im[i2] = u0i - ti;
    tr = cc * u3r - sc * u3i; ti = cc * u3i + sc * u3r;
    re[i1] = u1r + tr; im[i1] = u1i + ti;
    re[i3] = u1r - tr; im[i3] = u1i - ti;
    __syncthreads();
  }
}

// ---------------- window + 1/wsum + twiddle tables (recomputed every call) ----------------
__global__ void k_tables(float* __restrict__ win, float* __restrict__ wsinv,
                         float* __restrict__ twc, float* __restrict__ tws) {
  int tid = threadIdx.x;
  for (int i = tid; i < NFFT_SZ; i += 256) {
    double w = 0.5 - 0.5 * cos((TWO_PI_D / (double)NFFT_SZ) * (double)i);
    win[i] = (float)w;
  }
  for (int i = tid; i < 512; i += 256) {
    double th = (TWO_PI_D / (double)NFFT_SZ) * (double)i;
    twc[i] = (float)cos(th);
    tws[i] = (float)sin(th);
  }
  for (int pc = tid; pc < CHUNKSZ; pc += 256) {
    int t1 = min(NFR - 1, pc >> 8);
    int t0 = (pc > NFFT_SZ - 1) ? ((pc - 768) >> 8) : 0;
    float ws = 0.f;
    for (int tt = t0; tt <= t1; ++tt) {
      int n = pc - tt * HOP_SZ;
      double w = 0.5 - 0.5 * cos((TWO_PI_D / (double)NFFT_SZ) * (double)n);
      float wf = (float)w;
      ws += wf * wf;
    }
    wsinv[pc] = 1.0f / fmaxf(ws, 1e-8f);
  }
}

// ---------------- emb @ wx_emb precompute: embxg[b][col] ----------------
__global__ void k_embxg(const float* __restrict__ emb_table, const int* __restrict__ effect_id,
                        const float* __restrict__ wx, float* __restrict__ embxg) {
  int b = blockIdx.x;
  int tid = threadIdx.x;
  int e_id = effect_id[b];
  const float* ev = emb_table + (size_t)e_id * EDIM;
  #pragma unroll
  for (int j = 0; j < 3; ++j) {
    int col = tid + 256 * j;
    float acc = 0.f;
    #pragma unroll 4
    for (int e = 0; e < EDIM; ++e)
      acc += ev[e] * wx[(size_t)(NFREQ + e) * GDIM + col];
    embxg[(size_t)b * GDIM + col] = acc;
  }
}

// ---------------- forward STFT: one frame per block ----------------
__global__ void k_stft(const float* __restrict__ audio, const float* __restrict__ win,
                       const float* __restrict__ gtwc, const float* __restrict__ gtws,
                       float* __restrict__ spec) {
  int fr = blockIdx.x;
  int b   = fr / (NK * NFR);
  int rem = fr % (NK * NFR);
  int k = rem / NFR, t = rem % NFR;
  int tid = threadIdx.x;
  __shared__ float xin[NFFT_SZ];
  __shared__ float re[NFFT_SZ], im[NFFT_SZ];
  __shared__ float twc[512], tws[512];
  for (int i = tid; i < 512; i += 256) { twc[i] = gtwc[i]; tws[i] = gtws[i]; }
  int start = k * STRIDESZ + t * HOP_SZ;
  for (int i = tid; i < NFFT_SZ; i += 256) {
    int pos = start + i;
    float v = (pos < T_LEN) ? audio[b * T_LEN + pos] : 0.f;
    xin[i] = v * win[i];
  }
  __syncthreads();
  for (int i = tid; i < NFFT_SZ; i += 256) {
    int rv = (int)(__brev((unsigned)i) >> 22);
    re[i] = xin[rv];
    im[i] = 0.f;
  }
  __syncthreads();
  fft1024(re, im, twc, tws, tid, -1.f);
  float* sp = spec + (size_t)fr * FR_STRIDE;
  for (int f = tid; f < NFREQ; f += 256) {
    sp[2 * f]     = re[f];
    sp[2 * f + 1] = im[f];
  }
}

// ---------------- xg = [mag | emb] @ wx, tiled 16 frames/block ----------------
#define XG_MT 16
__global__ __launch_bounds__(256) void k_xg(
    const float* __restrict__ spec, const float* __restrict__ embxg,
    const float* __restrict__ wx, float* __restrict__ xg) {
  int fr0 = blockIdx.x * XG_MT;
  int tid = threadIdx.x;
  __shared__ __align__(16) float xs[XG_MT][520];   // mags, cols 513..519 zero-padded
  for (int m = 0; m < XG_MT; ++m) {
    int fr = fr0 + m;
    if (fr < NFRAMES) {
      const float* sp = spec + (size_t)fr * FR_STRIDE;
      for (int f = tid; f < NFREQ; f += 256) {
        float r = sp[2 * f], iv = sp[2 * f + 1];
        xs[m][f] = sqrtf(r * r + iv * iv);
      }
    } else {
      for (int f = tid; f < NFREQ; f += 256) xs[m][f] = 0.f;
    }
    if (tid < 7) xs[m][NFREQ + tid] = 0.f;
  }
  __syncthreads();
  float acc0[XG_MT], acc1[XG_MT], acc2[XG_MT];
  #pragma unroll
  for (int m = 0; m < XG_MT; ++m) { acc0[m] = 0.f; acc1[m] = 0.f; acc2[m] = 0.f; }
  for (int kb = 0; kb < 516; kb += 4) {
    const float* w = wx + (size_t)kb * GDIM + tid;
    float wa0 = w[0],        wa1 = w[256],        wa2 = w[512];
    float wb0 = w[GDIM],     wb1 = w[GDIM+256],   wb2 = w[GDIM+512];
    float wc0 = w[2*GDIM],   wc1 = w[2*GDIM+256], wc2 = w[2*GDIM+512];
    float wd0 = w[3*GDIM],   wd1 = w[3*GDIM+256], wd2 = w[3*GDIM+512];
    #pragma unroll
    for (int m = 0; m < XG_MT; ++m) {
      float4 xv = *(const float4*)&xs[m][kb];
      acc0[m] += xv.x * wa0; acc1[m] += xv.x * wa1; acc2[m] += xv.x * wa2;
      acc0[m] += xv.y * wb0; acc1[m] += xv.y * wb1; acc2[m] += xv.y * wb2;
      acc0[m] += xv.z * wc0; acc1[m] += xv.z * wc1; acc2[m] += xv.z * wc2;
      acc0[m] += xv.w * wd0; acc1[m] += xv.w * wd1; acc2[m] += xv.w * wd2;
    }
  }
  for (int m = 0; m < XG_MT; ++m) {
    int fr = fr0 + m;
    if (fr >= NFRAMES) break;
    int b = fr / KCF;
    const float* eb = embxg + (size_t)b * GDIM;
    float* xo = xg + (size_t)fr * GDIM;
    xo[tid]       = acc0[m] + eb[tid];
    xo[tid + 256] = acc1[m] + eb[tid + 256];
    xo[tid + 512] = acc2[m] + eb[tid + 512];
  }
}

// ---------------- GRU: 768 threads/block, 1 output column per thread ----------------
// 252 blocks (5 chunks each) => 12 waves/CU. K=256 reduction with LDS-broadcast h.
#define GRU_CT 5
__global__ __launch_bounds__(768) void k_gru(
    const float* __restrict__ xg, const float* __restrict__ wh,
    const float* __restrict__ bias, float* __restrict__ hs) {
  int c0 = blockIdx.x * GRU_CT;
  int tid = threadIdx.x;                 // 0..767 == output column (gate*256+unit)
  __shared__ __align__(16) float h[GRU_CT][HDIM];    // 5 KB
  __shared__ float hg[GRU_CT][GDIM];                 // 15 KB
  float* hflat = &h[0][0];
  for (int i = tid; i < GRU_CT * HDIM; i += 768) hflat[i] = 0.f;
  float bcol = bias[tid];
  __syncthreads();
  for (int t = 0; t < NFR; ++t) {
    float acc[GRU_CT];
    #pragma unroll
    for (int c = 0; c < GRU_CT; ++c) acc[c] = bcol;
    const float* wcol = wh + tid;
    #pragma unroll 2
    for (int k = 0; k < HDIM; k += 4) {
      float w0 = wcol[(size_t)(k + 0) * GDIM];
      float w1 = wcol[(size_t)(k + 1) * GDIM];
      float w2 = wcol[(size_t)(k + 2) * GDIM];
      float w3 = wcol[(size_t)(k + 3) * GDIM];
      #pragma unroll
      for (int c = 0; c < GRU_CT; ++c) {
        float4 hv = *(const float4*)&h[c][k];     // broadcast read
        acc[c] += hv.x * w0 + hv.y * w1 + hv.z * w2 + hv.w * w3;
      }
    }
    #pragma unroll
    for (int c = 0; c < GRU_CT; ++c) hg[c][tid] = acc[c];
    __syncthreads();
    // nonlinearity: 1280 (chunk,unit) items over 768 threads
    for (int i = tid; i < GRU_CT * HDIM; i += 768) {
      int c = i >> 8, u = i & 255;
      int cb = c0 + c;
      if (cb < NCHUNKS) {
        const float* xgt = xg + (size_t)(cb * NFR + t) * GDIM;
        float z = 1.f / (1.f + expf(-(xgt[u] + hg[c][u])));
        float r = 1.f / (1.f + expf(-(xgt[u + 256] + hg[c][u + 256])));
        float n = tanhf(xgt[u + 512] + r * hg[c][u + 512]);
        float hn = (1.f - z) * n + z * h[c][u];
        h[c][u] = hn;                    // unique (c,u) per thread: safe in-place
        hs[(size_t)(cb * NFR + t) * HDIM + u] = hn;
      }
    }
    __syncthreads();
  }
}

// ---------------- projection + FiLM modulation, tiled 8 frames/block ----------------
#define PJ_MT 8
__global__ __launch_bounds__(256) void k_projmod(
    const float* __restrict__ hs, const float* __restrict__ pw,
    const float* __restrict__ pb, float* __restrict__ spec) {
  int fr0 = blockIdx.x * PJ_MT;
  int tid = threadIdx.x;
  __shared__ __align__(16) float h[PJ_MT][HDIM];     // 8 KB
  __shared__ float gb[PJ_MT][PDIM];                  // 32.8 KB
  #pragma unroll
  for (int m = 0; m < PJ_MT; ++m)
    h[m][tid] = hs[(size_t)(fr0 + m) * HDIM + tid];
  __syncthreads();
  float pb0 = pb[tid], pb1 = pb[tid + 256], pb2 = pb[tid + 512], pb3 = pb[tid + 768];
  float a0[PJ_MT], a1[PJ_MT], a2[PJ_MT], a3[PJ_MT];
  #pragma unroll
  for (int m = 0; m < PJ_MT; ++m) { a0[m] = pb0; a1[m] = pb1; a2[m] = pb2; a3[m] = pb3; }
  for (int kb = 0; kb < HDIM; kb += 4) {
    const float* w = pw + (size_t)kb * PDIM + tid;
    float wa0 = w[0],      wa1 = w[256],      wa2 = w[512],      wa3 = w[768];
    float wb0 = w[PDIM],   wb1 = w[PDIM+256], wb2 = w[PDIM+512], wb3 = w[PDIM+768];
    float wc0 = w[2*PDIM], wc1 = w[2*PDIM+256], wc2 = w[2*PDIM+512], wc3 = w[2*PDIM+768];
    float wd0 = w[3*PDIM], wd1 = w[3*PDIM+256], wd2 = w[3*PDIM+512], wd3 = w[3*PDIM+768];
    #pragma unroll
    for (int m = 0; m < PJ_MT; ++m) {
      float4 hv = *(const float4*)&h[m][kb];
      a0[m] += hv.x * wa0; a1[m] += hv.x * wa1; a2[m] += hv.x * wa2; a3[m] += hv.x * wa3;
      a0[m] += hv.y * wb0; a1[m] += hv.y * wb1; a2[m] += hv.y * wb2; a3[m] += hv.y * wb3;
      a0[m] += hv.z * wc0; a1[m] += hv.z * wc1; a2[m] += hv.z * wc2; a3[m] += hv.z * wc3;
      a0[m] += hv.w * wd0; a1[m] += hv.w * wd1; a2[m] += hv.w * wd2; a3[m] += hv.w * wd3;
    }
  }
  #pragma unroll
  for (int m = 0; m < PJ_MT; ++m) {
    gb[m][tid]       = a0[m];
    gb[m][tid + 256] = a1[m];
    gb[m][tid + 512] = a2[m];
    gb[m][tid + 768] = a3[m];   // max col 1023
  }
  if (tid < 16) {
    int m = tid >> 1, col = 1024 + (tid & 1);
    float a = pb[col];
    for (int k = 0; k < HDIM; ++k) a += h[m][k] * pw[(size_t)k * PDIM + col];
    gb[m][col] = a;
  }
  __syncthreads();
  #pragma unroll 2
  for (int m = 0; m < PJ_MT; ++m) {
    float* sp = spec + (size_t)(fr0 + m) * FR_STRIDE;
    for (int f = tid; f < NFREQ; f += 256) {
      float r = sp[2 * f], iv = sp[2 * f + 1];
      float mag = sqrtf(r * r + iv * iv);
      float mm = gb[m][f] * mag + gb[m][NFREQ + f];
      float nr, ni;
      if (mag > 0.f) {
        float s = mm / mag;
        nr = r * s; ni = iv * s;
      } else {
        nr = mm; ni = 0.f;   // angle(0)=0
      }
      sp[2 * f]     = nr;
      sp[2 * f + 1] = ni;
    }
  }
}

// ---------------- inverse FFT + win/wsum scaling; overwrite frame slot with y ----------------
__global__ void k_istft(float* __restrict__ spec, const float* __restrict__ win,
                        const float* __restrict__ wsinv,
                        const float* __restrict__ gtwc, const float* __restrict__ gtws) {
  int fr = blockIdx.x;
  int tid = threadIdx.x;
  int t = fr % NFR;
  __shared__ float sre[NFREQ], sim[NFREQ];
  __shared__ float re[NFFT_SZ], im[NFFT_SZ];
  __shared__ float twc[512], tws[512];
  for (int i = tid; i < 512; i += 256) { twc[i] = gtwc[i]; tws[i] = gtws[i]; }
  float* sp = spec + (size_t)fr * FR_STRIDE;
  for (int f = tid; f < NFREQ; f += 256) {
    sre[f] = sp[2 * f];
    float iv = sp[2 * f + 1];
    sim[f] = (f == 0 || f == NFREQ - 1) ? 0.f : iv;  // irfft ignores DC/Nyquist imag
  }
  __syncthreads();
  for (int i = tid; i < NFFT_SZ; i += 256) {
    int src = (int)(__brev((unsigned)i) >> 22);
    float r, iv;
    if (src <= 512) { r = sre[src]; iv = sim[src]; }
    else            { r = sre[NFFT_SZ - src]; iv = -sim[NFFT_SZ - src]; }
    re[i] = r; im[i] = iv;
  }
  __syncthreads();
  fft1024(re, im, twc, tws, tid, +1.f);
  for (int i = tid; i < NFFT_SZ; i += 256) {
    float y = re[i] * (1.0f / (float)NFFT_SZ);
    int pc = t * HOP_SZ + i;
    sp[i] = y * win[i] * wsinv[pc];
  }
}

// ---------------- deterministic gather overlap-add ----------------
__global__ void k_gather(const float* __restrict__ ybuf, float* __restrict__ out) {
  int gid = blockIdx.x * 256 + threadIdx.x;
  if (gid >= NB * T_LEN) return;
  int b = gid / T_LEN, pos = gid % T_LEN;
  float acc = 0.f;
  int k_hi = min(NK - 1, pos / STRIDESZ);
  int k_lo = (pos >= CHUNKSZ) ? ((pos - (CHUNKSZ - 1) + (STRIDESZ - 1)) / STRIDESZ) : 0;
  for (int k = k_lo; k <= k_hi; ++k) {
    int pc = pos - k * STRIDESZ;
    int t1 = min(NFR - 1, pc >> 8);
    int t0 = (pc > NFFT_SZ - 1) ? ((pc - 768) >> 8) : 0;
    int frbase = (b * NK + k) * NFR;
    for (int tt = t0; tt <= t1; ++tt) {
      acc += ybuf[(size_t)(frbase + tt) * FR_STRIDE + (pc - tt * HOP_SZ)];
    }
  }
  out[gid] = acc;
}

// ---------------- launch ----------------
extern "C" void kernel_launch(void* const* d_in, const int* in_sizes, int n_in,
                              void* d_out, int out_size, void* d_ws, size_t ws_size,
                              hipStream_t stream) {
  const float* audio     = (const float*)d_in[0];
  const float* emb_table = (const float*)d_in[1];
  const float* gru_wx    = (const float*)d_in[2];
  const float* gru_wh    = (const float*)d_in[3];
  const float* gru_b     = (const float*)d_in[4];
  const float* proj_w    = (const float*)d_in[5];
  const float* proj_b    = (const float*)d_in[6];
  const int*   effect_id = (const int*)d_in[7];
  float* out = (float*)d_out;

  float* ws    = (float*)d_ws;
  float* spec  = ws;                                   // NFRAMES*1026
  float* xg    = ws + (size_t)NFRAMES * FR_STRIDE;     // NFRAMES*768
  float* hs    = xg + (size_t)NFRAMES * GDIM;          // NFRAMES*256
  float* win   = hs + (size_t)NFRAMES * HDIM;          // 1024
  float* wsinv = win + NFFT_SZ;                        // 4096
  float* twc   = wsinv + CHUNKSZ;                      // 512
  float* tws   = twc + 512;                            // 512
  float* embxg = tws + 512;                            // 8*768

  k_tables <<<1, 256, 0, stream>>>(win, wsinv, twc, tws);
  k_embxg  <<<NB, 256, 0, stream>>>(emb_table, effect_id, gru_wx, embxg);
  k_stft   <<<NFRAMES, 256, 0, stream>>>(audio, win, twc, tws, spec);
  k_xg     <<<(NFRAMES + XG_MT - 1) / XG_MT, 256, 0, stream>>>(spec, embxg, gru_wx, xg);
  k_gru    <<<(NCHUNKS + GRU_CT - 1) / GRU_CT, 768, 0, stream>>>(xg, gru_wh, gru_b, hs);
  k_projmod<<<NFRAMES / PJ_MT, 256, 0, stream>>>(hs, proj_w, proj_b, spec);
  k_istft  <<<NFRAMES, 256, 0, stream>>>(spec, win, wsinv, twc, tws);
  k_gather <<<(NB * T_LEN + 255) / 256, 256, 0, stream>>>(spec, out);
}

// Round 5
// 780.366 us; speedup vs baseline: 3.0783x; 1.1368x over previous
//
#include <hip/hip_runtime.h>
#include <math.h>

#define T_LEN    480000
#define NB       8
#define NK       157      // chunks per batch
#define CHUNKSZ  4096
#define STRIDESZ 3072
#define NFFT_SZ  1024
#define HOP_SZ   256
#define NFREQ    513
#define NFR      13       // frames per chunk
#define HDIM     256
#define EDIM     128
#define XDIM     641      // NFREQ + EDIM
#define GDIM     768      // 3*HDIM
#define PDIM     1026     // 2*NFREQ
#define FR_STRIDE 1026    // floats per frame slot in spec buffer
#define NFRAMES  (NB*NK*NFR)   // 16328
#define NCHUNKS  (NB*NK)       // 1256
#define KCF      2041          // NK*NFR, frames per batch

// xg-GEMM tiling
#define XG_KS    17            // K-steps of 32 (K padded 516 -> 544)
#define XG_NB    3             // N blocks of 256 (768 total)

#define TWO_PI_D 6.283185307179586

typedef short bf16x8 __attribute__((ext_vector_type(8)));
typedef float f32x4  __attribute__((ext_vector_type(4)));

// split fp32 into hi/lo bf16 (truncation; residual captures dropped bits)
__device__ __forceinline__ void split_bf16(float v, short& hi, short& lo) {
  unsigned u = __float_as_uint(v);
  hi = (short)(u >> 16);
  float fh = __uint_as_float(u & 0xFFFF0000u);
  float res = v - fh;
  lo = (short)(__float_as_uint(res) >> 16);
}

// ---------------- radix-2 DIT FFT, fused stage pairs (5 syncs), table twiddles ----------------
__device__ __forceinline__ void fft1024(float* re, float* im,
                                        const float* twc, const float* tws,
                                        int tid, float dir) {
  #pragma unroll
  for (int s = 1; s <= 9; s += 2) {
    int half = 1 << (s - 1);            // 1,4,16,64,256
    int p   = tid & (half - 1);
    int grp = tid >> (s - 1);
    int i0  = grp * 4 * half + p;
    int i1  = i0 + half;
    int i2  = i0 + 2 * half;
    int i3  = i0 + 3 * half;
    float r0 = re[i0], q0 = im[i0], r1 = re[i1], q1 = im[i1];
    float r2 = re[i2], q2 = im[i2], r3 = re[i3], q3 = im[i3];
    int qa = p << (10 - s);
    float ca = twc[qa], sa = dir * tws[qa];
    float tr = ca * r1 - sa * q1, ti = ca * q1 + sa * r1;
    float u0r = r0 + tr, u0i = q0 + ti;
    float u1r = r0 - tr, u1i = q0 - ti;
    tr = ca * r3 - sa * q3; ti = ca * q3 + sa * r3;
    float u2r = r2 + tr, u2i = q2 + ti;
    float u3r = r2 - tr, u3i = q2 - ti;
    int qb = p << (9 - s);
    int qc = (p + half) << (9 - s);
    float cb = twc[qb], sb = dir * tws[qb];
    float cc = twc[qc], sc = dir * tws[qc];
    tr = cb * u2r - sb * u2i; ti = cb * u2i + sb * u2r;
    re[i0] = u0r + tr; im[i0] = u0i + ti;
    re[i2] = u0r - tr; im[i2] = u0i - ti;
    tr = cc * u3r - sc * u3i; ti = cc * u3i + sc * u3r;
    re[i1] = u1r + tr; im[i1] = u1i + ti;
    re[i3] = u1r - tr; im[i3] = u1i - ti;
    __syncthreads();
  }
}

// ---------------- window + 1/wsum + twiddle tables (recomputed every call) ----------------
__global__ void k_tables(float* __restrict__ win, float* __restrict__ wsinv,
                         float* __restrict__ twc, float* __restrict__ tws) {
  int tid = threadIdx.x;
  for (int i = tid; i < NFFT_SZ; i += 256) {
    double w = 0.5 - 0.5 * cos((TWO_PI_D / (double)NFFT_SZ) * (double)i);
    win[i] = (float)w;
  }
  for (int i = tid; i < 512; i += 256) {
    double th = (TWO_PI_D / (double)NFFT_SZ) * (double)i;
    twc[i] = (float)cos(th);
    tws[i] = (float)sin(th);
  }
  for (int pc = tid; pc < CHUNKSZ; pc += 256) {
    int t1 = min(NFR - 1, pc >> 8);
    int t0 = (pc > NFFT_SZ - 1) ? ((pc - 768) >> 8) : 0;
    float ws = 0.f;
    for (int tt = t0; tt <= t1; ++tt) {
      int n = pc - tt * HOP_SZ;
      double w = 0.5 - 0.5 * cos((TWO_PI_D / (double)NFFT_SZ) * (double)n);
      float wf = (float)w;
      ws += wf * wf;
    }
    wsinv[pc] = 1.0f / fmaxf(ws, 1e-8f);
  }
}

// ---------------- one-time wx transpose+split into blocked bf16 hi/lo ----------------
// wxb[nb][ks][col][k] layout; k_g = ks*32+k (<=543, all < 641 valid rows of wx)
__global__ void k_prep(const float* __restrict__ wx,
                       short* __restrict__ wxb_hi, short* __restrict__ wxb_lo) {
  int id = blockIdx.x * 256 + threadIdx.x;
  if (id >= XG_NB * XG_KS * 256) return;
  int nb  = id / (XG_KS * 256);
  int ks  = (id / 256) % XG_KS;
  int col = id % 256;
  int col_g = nb * 256 + col;
  size_t base = (size_t)id * 32;
  for (int j = 0; j < 32; ++j) {
    int k_g = ks * 32 + j;
    float v = wx[(size_t)k_g * GDIM + col_g];
    short hi, lo;
    split_bf16(v, hi, lo);
    wxb_hi[base + j] = hi;
    wxb_lo[base + j] = lo;
  }
}

// ---------------- emb @ wx_emb precompute: embxg[b][col] ----------------
__global__ void k_embxg(const float* __restrict__ emb_table, const int* __restrict__ effect_id,
                        const float* __restrict__ wx, float* __restrict__ embxg) {
  int b = blockIdx.x;
  int tid = threadIdx.x;
  int e_id = effect_id[b];
  const float* ev = emb_table + (size_t)e_id * EDIM;
  #pragma unroll
  for (int j = 0; j < 3; ++j) {
    int col = tid + 256 * j;
    float acc = 0.f;
    #pragma unroll 4
    for (int e = 0; e < EDIM; ++e)
      acc += ev[e] * wx[(size_t)(NFREQ + e) * GDIM + col];
    embxg[(size_t)b * GDIM + col] = acc;
  }
}

// ---------------- forward STFT: one frame per block ----------------
__global__ void k_stft(const float* __restrict__ audio, const float* __restrict__ win,
                       const float* __restrict__ gtwc, const float* __restrict__ gtws,
                       float* __restrict__ spec) {
  int fr = blockIdx.x;
  int b   = fr / (NK * NFR);
  int rem = fr % (NK * NFR);
  int k = rem / NFR, t = rem % NFR;
  int tid = threadIdx.x;
  __shared__ float xin[NFFT_SZ];
  __shared__ float re[NFFT_SZ], im[NFFT_SZ];
  __shared__ float twc[512], tws[512];
  for (int i = tid; i < 512; i += 256) { twc[i] = gtwc[i]; tws[i] = gtws[i]; }
  int start = k * STRIDESZ + t * HOP_SZ;
  for (int i = tid; i < NFFT_SZ; i += 256) {
    int pos = start + i;
    float v = (pos < T_LEN) ? audio[b * T_LEN + pos] : 0.f;
    xin[i] = v * win[i];
  }
  __syncthreads();
  for (int i = tid; i < NFFT_SZ; i += 256) {
    int rv = (int)(__brev((unsigned)i) >> 22);
    re[i] = xin[rv];
    im[i] = 0.f;
  }
  __syncthreads();
  fft1024(re, im, twc, tws, tid, -1.f);
  float* sp = spec + (size_t)fr * FR_STRIDE;
  for (int f = tid; f < NFREQ; f += 256) {
    sp[2 * f]     = re[f];
    sp[2 * f + 1] = im[f];
  }
}

// ---------------- xg GEMM via MFMA bf16x3 split ----------------
// C[64 frames x 256 cols] per block; grid = 256 mb x 3 nb. BK=32.
__global__ __launch_bounds__(256) void k_xg(
    const float* __restrict__ spec, const float* __restrict__ embxg,
    const short* __restrict__ wxb_hi, const short* __restrict__ wxb_lo,
    float* __restrict__ xg) {
  int nb  = blockIdx.x % XG_NB;
  int mb  = blockIdx.x / XG_NB;
  int fr0 = mb * 64;
  int tid = threadIdx.x;
  int lane = tid & 63;
  int wv   = tid >> 6;

  __shared__ __align__(16) short lsA[2][64 * 40];    // [plane][frame][k] pitch 40
  __shared__ __align__(16) short lsB[2][256 * 40];   // [plane][col][k]  pitch 40

  f32x4 acc[4][4];
  #pragma unroll
  for (int i = 0; i < 4; ++i)
    #pragma unroll
    for (int j = 0; j < 4; ++j)
      acc[i][j] = (f32x4){0.f, 0.f, 0.f, 0.f};

  int lrow = lane & 15;
  int lk8  = (lane >> 4) * 8;

  for (int ks = 0; ks < XG_KS; ++ks) {
    int k0 = ks * 32;
    // ---- stage A: 64 frames x 32 bins (mag, split) ----
    {
      int f = tid >> 2, q = tid & 3;
      int fr = fr0 + f;
      short hi[8], lo[8];
      #pragma unroll
      for (int j = 0; j < 8; ++j) {
        int bg = k0 + q * 8 + j;
        float m = 0.f;
        if (fr < NFRAMES && bg <= 512) {
          const float* sp = spec + (size_t)fr * FR_STRIDE + 2 * bg;
          float rr = sp[0], ii = sp[1];
          m = sqrtf(rr * rr + ii * ii);
        }
        split_bf16(m, hi[j], lo[j]);
      }
      int off = f * 40 + q * 8;
      *(bf16x8*)&lsA[0][off] = *(bf16x8*)hi;
      *(bf16x8*)&lsA[1][off] = *(bf16x8*)lo;
    }
    // ---- stage B: 256 cols x 32 k, hi+lo ----
    {
      const short* gh = wxb_hi + (((size_t)nb * XG_KS + ks) * 256 + tid) * 32;
      const short* gl = wxb_lo + (((size_t)nb * XG_KS + ks) * 256 + tid) * 32;
      int off = tid * 40;
      #pragma unroll
      for (int i = 0; i < 4; ++i) {
        *(bf16x8*)&lsB[0][off + 8 * i] = *(const bf16x8*)(gh + 8 * i);
        *(bf16x8*)&lsB[1][off + 8 * i] = *(const bf16x8*)(gl + 8 * i);
      }
    }
    __syncthreads();
    // ---- fragments + MFMA ----
    bf16x8 aH[4], aL[4], bH[4], bL[4];
    #pragma unroll
    for (int mt = 0; mt < 4; ++mt) {
      int off = (16 * mt + lrow) * 40 + lk8;
      aH[mt] = *(const bf16x8*)&lsA[0][off];
      aL[mt] = *(const bf16x8*)&lsA[1][off];
    }
    #pragma unroll
    for (int nt = 0; nt < 4; ++nt) {
      int col = wv * 64 + nt * 16 + lrow;
      int off = col * 40 + lk8;
      bH[nt] = *(const bf16x8*)&lsB[0][off];
      bL[nt] = *(const bf16x8*)&lsB[1][off];
    }
    #pragma unroll
    for (int mt = 0; mt < 4; ++mt)
      #pragma unroll
      for (int nt = 0; nt < 4; ++nt) {
        acc[mt][nt] = __builtin_amdgcn_mfma_f32_16x16x32_bf16(aH[mt], bH[nt], acc[mt][nt], 0, 0, 0);
        acc[mt][nt] = __builtin_amdgcn_mfma_f32_16x16x32_bf16(aH[mt], bL[nt], acc[mt][nt], 0, 0, 0);
        acc[mt][nt] = __builtin_amdgcn_mfma_f32_16x16x32_bf16(aL[mt], bH[nt], acc[mt][nt], 0, 0, 0);
      }
    __syncthreads();
  }

  // ---- epilogue: add embxg, store ----
  int ncol0 = nb * 256 + wv * 64;
  #pragma unroll
  for (int mt = 0; mt < 4; ++mt) {
    #pragma unroll
    for (int r = 0; r < 4; ++r) {
      int fr = fr0 + mt * 16 + (lane >> 4) * 4 + r;
      if (fr < NFRAMES) {
        int b = fr / KCF;
        #pragma unroll
        for (int nt = 0; nt < 4; ++nt) {
          int col = ncol0 + nt * 16 + (lane & 15);
          xg[(size_t)fr * GDIM + col] = acc[mt][nt][r] + embxg[(size_t)b * GDIM + col];
        }
      }
    }
  }
}

// ---------------- GRU: 768 threads/block, 1 output column per thread ----------------
#define GRU_CT 5
__global__ __launch_bounds__(768) void k_gru(
    const float* __restrict__ xg, const float* __restrict__ wh,
    const float* __restrict__ bias, float* __restrict__ hs) {
  int c0 = blockIdx.x * GRU_CT;
  int tid = threadIdx.x;                 // 0..767 == output column (gate*256+unit)
  __shared__ __align__(16) float h[GRU_CT][HDIM];    // 5 KB
  __shared__ float hg[GRU_CT][GDIM];                 // 15 KB
  float* hflat = &h[0][0];
  for (int i = tid; i < GRU_CT * HDIM; i += 768) hflat[i] = 0.f;
  float bcol = bias[tid];
  __syncthreads();
  for (int t = 0; t < NFR; ++t) {
    float acc[GRU_CT];
    #pragma unroll
    for (int c = 0; c < GRU_CT; ++c) acc[c] = bcol;
    const float* wcol = wh + tid;
    #pragma unroll 2
    for (int k = 0; k < HDIM; k += 4) {
      float w0 = wcol[(size_t)(k + 0) * GDIM];
      float w1 = wcol[(size_t)(k + 1) * GDIM];
      float w2 = wcol[(size_t)(k + 2) * GDIM];
      float w3 = wcol[(size_t)(k + 3) * GDIM];
      #pragma unroll
      for (int c = 0; c < GRU_CT; ++c) {
        float4 hv = *(const float4*)&h[c][k];     // broadcast read
        acc[c] += hv.x * w0 + hv.y * w1 + hv.z * w2 + hv.w * w3;
      }
    }
    #pragma unroll
    for (int c = 0; c < GRU_CT; ++c) hg[c][tid] = acc[c];
    __syncthreads();
    for (int i = tid; i < GRU_CT * HDIM; i += 768) {
      int c = i >> 8, u = i & 255;
      int cb = c0 + c;
      if (cb < NCHUNKS) {
        const float* xgt = xg + (size_t)(cb * NFR + t) * GDIM;
        float z = 1.f / (1.f + expf(-(xgt[u] + hg[c][u])));
        float r = 1.f / (1.f + expf(-(xgt[u + 256] + hg[c][u + 256])));
        float n = tanhf(xgt[u + 512] + r * hg[c][u + 512]);
        float hn = (1.f - z) * n + z * h[c][u];
        h[c][u] = hn;
        hs[(size_t)(cb * NFR + t) * HDIM + u] = hn;
      }
    }
    __syncthreads();
  }
}

// ---------------- projection + FiLM modulation, tiled 8 frames/block ----------------
#define PJ_MT 8
__global__ __launch_bounds__(256) void k_projmod(
    const float* __restrict__ hs, const float* __restrict__ pw,
    const float* __restrict__ pb, float* __restrict__ spec) {
  int fr0 = blockIdx.x * PJ_MT;
  int tid = threadIdx.x;
  __shared__ __align__(16) float h[PJ_MT][HDIM];     // 8 KB
  __shared__ float gb[PJ_MT][PDIM];                  // 32.8 KB
  #pragma unroll
  for (int m = 0; m < PJ_MT; ++m)
    h[m][tid] = hs[(size_t)(fr0 + m) * HDIM + tid];
  __syncthreads();
  float pb0 = pb[tid], pb1 = pb[tid + 256], pb2 = pb[tid + 512], pb3 = pb[tid + 768];
  float a0[PJ_MT], a1[PJ_MT], a2[PJ_MT], a3[PJ_MT];
  #pragma unroll
  for (int m = 0; m < PJ_MT; ++m) { a0[m] = pb0; a1[m] = pb1; a2[m] = pb2; a3[m] = pb3; }
  for (int kb = 0; kb < HDIM; kb += 4) {
    const float* w = pw + (size_t)kb * PDIM + tid;
    float wa0 = w[0],      wa1 = w[256],      wa2 = w[512],      wa3 = w[768];
    float wb0 = w[PDIM],   wb1 = w[PDIM+256], wb2 = w[PDIM+512], wb3 = w[PDIM+768];
    float wc0 = w[2*PDIM], wc1 = w[2*PDIM+256], wc2 = w[2*PDIM+512], wc3 = w[2*PDIM+768];
    float wd0 = w[3*PDIM], wd1 = w[3*PDIM+256], wd2 = w[3*PDIM+512], wd3 = w[3*PDIM+768];
    #pragma unroll
    for (int m = 0; m < PJ_MT; ++m) {
      float4 hv = *(const float4*)&h[m][kb];
      a0[m] += hv.x * wa0; a1[m] += hv.x * wa1; a2[m] += hv.x * wa2; a3[m] += hv.x * wa3;
      a0[m] += hv.y * wb0; a1[m] += hv.y * wb1; a2[m] += hv.y * wb2; a3[m] += hv.y * wb3;
      a0[m] += hv.z * wc0; a1[m] += hv.z * wc1; a2[m] += hv.z * wc2; a3[m] += hv.z * wc3;
      a0[m] += hv.w * wd0; a1[m] += hv.w * wd1; a2[m] += hv.w * wd2; a3[m] += hv.w * wd3;
    }
  }
  #pragma unroll
  for (int m = 0; m < PJ_MT; ++m) {
    gb[m][tid]       = a0[m];
    gb[m][tid + 256] = a1[m];
    gb[m][tid + 512] = a2[m];
    gb[m][tid + 768] = a3[m];   // max col 1023
  }
  if (tid < 16) {
    int m = tid >> 1, col = 1024 + (tid & 1);
    float a = pb[col];
    for (int k = 0; k < HDIM; ++k) a += h[m][k] * pw[(size_t)k * PDIM + col];
    gb[m][col] = a;
  }
  __syncthreads();
  #pragma unroll 2
  for (int m = 0; m < PJ_MT; ++m) {
    float* sp = spec + (size_t)(fr0 + m) * FR_STRIDE;
    for (int f = tid; f < NFREQ; f += 256) {
      float r = sp[2 * f], iv = sp[2 * f + 1];
      float mag = sqrtf(r * r + iv * iv);
      float mm = gb[m][f] * mag + gb[m][NFREQ + f];
      float nr, ni;
      if (mag > 0.f) {
        float s = mm / mag;
        nr = r * s; ni = iv * s;
      } else {
        nr = mm; ni = 0.f;   // angle(0)=0
      }
      sp[2 * f]     = nr;
      sp[2 * f + 1] = ni;
    }
  }
}

// ---------------- inverse FFT + win/wsum scaling; overwrite frame slot with y ----------------
__global__ void k_istft(float* __restrict__ spec, const float* __restrict__ win,
                        const float* __restrict__ wsinv,
                        const float* __restrict__ gtwc, const float* __restrict__ gtws) {
  int fr = blockIdx.x;
  int tid = threadIdx.x;
  int t = fr % NFR;
  __shared__ float sre[NFREQ], sim[NFREQ];
  __shared__ float re[NFFT_SZ], im[NFFT_SZ];
  __shared__ float twc[512], tws[512];
  for (int i = tid; i < 512; i += 256) { twc[i] = gtwc[i]; tws[i] = gtws[i]; }
  float* sp = spec + (size_t)fr * FR_STRIDE;
  for (int f = tid; f < NFREQ; f += 256) {
    sre[f] = sp[2 * f];
    float iv = sp[2 * f + 1];
    sim[f] = (f == 0 || f == NFREQ - 1) ? 0.f : iv;  // irfft ignores DC/Nyquist imag
  }
  __syncthreads();
  for (int i = tid; i < NFFT_SZ; i += 256) {
    int src = (int)(__brev((unsigned)i) >> 22);
    float r, iv;
    if (src <= 512) { r = sre[src]; iv = sim[src]; }
    else            { r = sre[NFFT_SZ - src]; iv = -sim[NFFT_SZ - src]; }
    re[i] = r; im[i] = iv;
  }
  __syncthreads();
  fft1024(re, im, twc, tws, tid, +1.f);
  for (int i = tid; i < NFFT_SZ; i += 256) {
    float y = re[i] * (1.0f / (float)NFFT_SZ);
    int pc = t * HOP_SZ + i;
    sp[i] = y * win[i] * wsinv[pc];
  }
}

// ---------------- deterministic gather overlap-add ----------------
__global__ void k_gather(const float* __restrict__ ybuf, float* __restrict__ out) {
  int gid = blockIdx.x * 256 + threadIdx.x;
  if (gid >= NB * T_LEN) return;
  int b = gid / T_LEN, pos = gid % T_LEN;
  float acc = 0.f;
  int k_hi = min(NK - 1, pos / STRIDESZ);
  int k_lo = (pos >= CHUNKSZ) ? ((pos - (CHUNKSZ - 1) + (STRIDESZ - 1)) / STRIDESZ) : 0;
  for (int k = k_lo; k <= k_hi; ++k) {
    int pc = pos - k * STRIDESZ;
    int t1 = min(NFR - 1, pc >> 8);
    int t0 = (pc > NFFT_SZ - 1) ? ((pc - 768) >> 8) : 0;
    int frbase = (b * NK + k) * NFR;
    for (int tt = t0; tt <= t1; ++tt) {
      acc += ybuf[(size_t)(frbase + tt) * FR_STRIDE + (pc - tt * HOP_SZ)];
    }
  }
  out[gid] = acc;
}

// ---------------- launch ----------------
extern "C" void kernel_launch(void* const* d_in, const int* in_sizes, int n_in,
                              void* d_out, int out_size, void* d_ws, size_t ws_size,
                              hipStream_t stream) {
  const float* audio     = (const float*)d_in[0];
  const float* emb_table = (const float*)d_in[1];
  const float* gru_wx    = (const float*)d_in[2];
  const float* gru_wh    = (const float*)d_in[3];
  const float* gru_b     = (const float*)d_in[4];
  const float* proj_w    = (const float*)d_in[5];
  const float* proj_b    = (const float*)d_in[6];
  const int*   effect_id = (const int*)d_in[7];
  float* out = (float*)d_out;

  float* ws    = (float*)d_ws;
  float* spec  = ws;                                   // NFRAMES*1026
  float* xg    = ws + (size_t)NFRAMES * FR_STRIDE;     // NFRAMES*768
  float* hs    = xg + (size_t)NFRAMES * GDIM;          // NFRAMES*256
  float* win   = hs + (size_t)NFRAMES * HDIM;          // 1024
  float* wsinv = win + NFFT_SZ;                        // 4096
  float* twc   = wsinv + CHUNKSZ;                      // 512
  float* tws   = twc + 512;                            // 512
  float* embxg = tws + 512;                            // 8*768
  short* wxb_hi = (short*)(embxg + NB * GDIM);         // 3*17*256*32 shorts
  short* wxb_lo = wxb_hi + (size_t)XG_NB * XG_KS * 256 * 32;

  k_tables <<<1, 256, 0, stream>>>(win, wsinv, twc, tws);
  k_embxg  <<<NB, 256, 0, stream>>>(emb_table, effect_id, gru_wx, embxg);
  k_prep   <<<(XG_NB * XG_KS * 256 + 255) / 256, 256, 0, stream>>>(gru_wx, wxb_hi, wxb_lo);
  k_stft   <<<NFRAMES, 256, 0, stream>>>(audio, win, twc, tws, spec);
  k_xg     <<<256 * XG_NB, 256, 0, stream>>>(spec, embxg, wxb_hi, wxb_lo, xg);
  k_gru    <<<(NCHUNKS + GRU_CT - 1) / GRU_CT, 768, 0, stream>>>(xg, gru_wh, gru_b, hs);
  k_projmod<<<NFRAMES / PJ_MT, 256, 0, stream>>>(hs, proj_w, proj_b, spec);
  k_istft  <<<NFRAMES, 256, 0, stream>>>(spec, win, wsinv, twc, tws);
  k_gather <<<(NB * T_LEN + 255) / 256, 256, 0, stream>>>(spec, out);
}

// Round 9
// 639.967 us; speedup vs baseline: 3.7537x; 1.2194x over previous
//
#include <hip/hip_runtime.h>
#include <math.h>

#define T_LEN    480000
#define NB       8
#define NK       157      // chunks per batch
#define CHUNKSZ  4096
#define STRIDESZ 3072
#define NFFT_SZ  1024
#define HOP_SZ   256
#define NFREQ    513
#define NFR      13       // frames per chunk
#define HDIM     256
#define EDIM     128
#define GDIM     768      // 3*HDIM
#define PDIM     1026     // 2*NFREQ
#define FR_STRIDE 1026    // bf16 shorts per frame slot in spec buffer (513 uints)
#define NFRAMES  (NB*NK*NFR)   // 16328
#define NCHUNKS  (NB*NK)       // 1256
#define KCF      2041          // NK*NFR, frames per batch

// xg-GEMM tiling
#define XG_KS    17            // K-steps of 32 (K padded 516 -> 544)
#define XG_NB    3             // N blocks of 256 (768 total)
// proj-GEMM tiling
#define PJ_KS    8             // K = 256
#define PJ_NB    5             // N blocks of 256 (1026 -> 1280 padded)
// GRU (VALU version, proven rounds 4-5)
#define GRU_CT   5

#define TWO_PI_D 6.283185307179586

typedef short bf16x8 __attribute__((ext_vector_type(8)));
typedef float f32x4  __attribute__((ext_vector_type(4)));

// split fp32 into hi/lo bf16 (truncation; residual captures dropped bits)
__device__ __forceinline__ void split_bf16(float v, short& hi, short& lo) {
  unsigned u = __float_as_uint(v);
  hi = (short)(u >> 16);
  float fh = __uint_as_float(u & 0xFFFF0000u);
  float res = v - fh;
  lo = (short)(__float_as_uint(res) >> 16);
}

__device__ __forceinline__ unsigned short f2bf(float v) {   // round-to-nearest-even
  unsigned u = __float_as_uint(v);
  u += 0x7FFFu + ((u >> 16) & 1u);
  return (unsigned short)(u >> 16);
}
__device__ __forceinline__ float bf2f(unsigned short b) {
  return __uint_as_float(((unsigned)b) << 16);
}

// ---------------- radix-2 DIT FFT, fused stage pairs (5 syncs), table twiddles ----------------
__device__ __forceinline__ void fft1024(float* re, float* im,
                                        const float* twc, const float* tws,
                                        int tid, float dir) {
  #pragma unroll
  for (int s = 1; s <= 9; s += 2) {
    int half = 1 << (s - 1);            // 1,4,16,64,256
    int p   = tid & (half - 1);
    int grp = tid >> (s - 1);
    int i0  = grp * 4 * half + p;
    int i1  = i0 + half;
    int i2  = i0 + 2 * half;
    int i3  = i0 + 3 * half;
    float r0 = re[i0], q0 = im[i0], r1 = re[i1], q1 = im[i1];
    float r2 = re[i2], q2 = im[i2], r3 = re[i3], q3 = im[i3];
    int qa = p << (10 - s);
    float ca = twc[qa], sa = dir * tws[qa];
    float tr = ca * r1 - sa * q1, ti = ca * q1 + sa * r1;
    float u0r = r0 + tr, u0i = q0 + ti;
    float u1r = r0 - tr, u1i = q0 - ti;
    tr = ca * r3 - sa * q3; ti = ca * q3 + sa * r3;
    float u2r = r2 + tr, u2i = q2 + ti;
    float u3r = r2 - tr, u3i = q2 - ti;
    int qb = p << (9 - s);
    int qc = (p + half) << (9 - s);
    float cb = twc[qb], sb = dir * tws[qb];
    float cc = twc[qc], sc = dir * tws[qc];
    tr = cb * u2r - sb * u2i; ti = cb * u2i + sb * u2r;
    re[i0] = u0r + tr; im[i0] = u0i + ti;
    re[i2] = u0r - tr; im[i2] = u0i - ti;
    tr = cc * u3r - sc * u3i; ti = cc * u3i + sc * u3r;
    re[i1] = u1r + tr; im[i1] = u1i + ti;
    re[i3] = u1r - tr; im[i3] = u1i - ti;
    __syncthreads();
  }
}

// ---------------- window + 1/wsum + twiddle tables (recomputed every call) ----------------
__global__ void k_tables(float* __restrict__ win, float* __restrict__ wsinv,
                         float* __restrict__ twc, float* __restrict__ tws) {
  int tid = threadIdx.x;
  for (int i = tid; i < NFFT_SZ; i += 256) {
    double w = 0.5 - 0.5 * cos((TWO_PI_D / (double)NFFT_SZ) * (double)i);
    win[i] = (float)w;
  }
  for (int i = tid; i < 512; i += 256) {
    double th = (TWO_PI_D / (double)NFFT_SZ) * (double)i;
    twc[i] = (float)cos(th);
    tws[i] = (float)sin(th);
  }
  for (int pc = tid; pc < CHUNKSZ; pc += 256) {
    int t1 = min(NFR - 1, pc >> 8);
    int t0 = (pc > NFFT_SZ - 1) ? ((pc - 768) >> 8) : 0;
    float ws = 0.f;
    for (int tt = t0; tt <= t1; ++tt) {
      int n = pc - tt * HOP_SZ;
      double w = 0.5 - 0.5 * cos((TWO_PI_D / (double)NFFT_SZ) * (double)n);
      float wf = (float)w;
      ws += wf * wf;
    }
    wsinv[pc] = 1.0f / fmaxf(ws, 1e-8f);
  }
}

// ---------------- one-time wx transpose+split into blocked bf16 hi/lo ----------------
__global__ void k_prep(const float* __restrict__ wx,
                       short* __restrict__ wxb_hi, short* __restrict__ wxb_lo) {
  int id = blockIdx.x * 256 + threadIdx.x;
  if (id >= XG_NB * XG_KS * 256) return;
  int nb  = id / (XG_KS * 256);
  int ks  = (id / 256) % XG_KS;
  int col = id % 256;
  int col_g = nb * 256 + col;
  size_t base = (size_t)id * 32;
  for (int j = 0; j < 32; ++j) {
    int k_g = ks * 32 + j;
    float v = wx[(size_t)k_g * GDIM + col_g];
    short hi, lo;
    split_bf16(v, hi, lo);
    wxb_hi[base + j] = hi;
    wxb_lo[base + j] = lo;
  }
}

// ---------------- pw transpose+split: pwb[nb][ks][col][32] hi/lo ----------------
__global__ void k_prep_pw(const float* __restrict__ pw,
                          short* __restrict__ pwb_hi, short* __restrict__ pwb_lo) {
  int id = blockIdx.x * 256 + threadIdx.x;   // over 5*8*256
  if (id >= PJ_NB * PJ_KS * 256) return;
  int nb  = id / (PJ_KS * 256);
  int ks  = (id / 256) % PJ_KS;
  int col = id % 256;
  int col_g = nb * 256 + col;
  size_t base = (size_t)id * 32;
  for (int j = 0; j < 32; ++j) {
    int k_g = ks * 32 + j;
    float v = (col_g < PDIM) ? pw[(size_t)k_g * PDIM + col_g] : 0.f;
    short hi, lo;
    split_bf16(v, hi, lo);
    pwb_hi[base + j] = hi;
    pwb_lo[base + j] = lo;
  }
}

// ---------------- emb @ wx_emb precompute: embxg[b][col] ----------------
__global__ void k_embxg(const float* __restrict__ emb_table, const int* __restrict__ effect_id,
                        const float* __restrict__ wx, float* __restrict__ embxg) {
  int b = blockIdx.x;
  int tid = threadIdx.x;
  int e_id = effect_id[b];
  const float* ev = emb_table + (size_t)e_id * EDIM;
  #pragma unroll
  for (int j = 0; j < 3; ++j) {
    int col = tid + 256 * j;
    float acc = 0.f;
    #pragma unroll 4
    for (int e = 0; e < EDIM; ++e)
      acc += ev[e] * wx[(size_t)(NFREQ + e) * GDIM + col];
    embxg[(size_t)b * GDIM + col] = acc;
  }
}

// ---------------- forward STFT: one frame per block; bf16 (r,i) packed per uint ----------------
__global__ void k_stft(const float* __restrict__ audio, const float* __restrict__ win,
                       const float* __restrict__ gtwc, const float* __restrict__ gtws,
                       unsigned* __restrict__ spec) {   // spec as uints: 513 per frame
  int fr = blockIdx.x;
  int b   = fr / (NK * NFR);
  int rem = fr % (NK * NFR);
  int k = rem / NFR, t = rem % NFR;
  int tid = threadIdx.x;
  __shared__ float xin[NFFT_SZ];
  __shared__ float re[NFFT_SZ], im[NFFT_SZ];
  __shared__ float twc[512], tws[512];
  for (int i = tid; i < 512; i += 256) { twc[i] = gtwc[i]; tws[i] = gtws[i]; }
  int start = k * STRIDESZ + t * HOP_SZ;
  for (int i = tid; i < NFFT_SZ; i += 256) {
    int pos = start + i;
    float v = (pos < T_LEN) ? audio[b * T_LEN + pos] : 0.f;
    xin[i] = v * win[i];
  }
  __syncthreads();
  for (int i = tid; i < NFFT_SZ; i += 256) {
    int rv = (int)(__brev((unsigned)i) >> 22);
    re[i] = xin[rv];
    im[i] = 0.f;
  }
  __syncthreads();
  fft1024(re, im, twc, tws, tid, -1.f);
  unsigned* sp = spec + (size_t)fr * (FR_STRIDE / 2);   // 513 uints
  for (int f = tid; f < NFREQ; f += 256) {
    unsigned pr = f2bf(re[f]);
    unsigned pi = f2bf(im[f]);
    sp[f] = (pi << 16) | pr;
  }
}

// ---------------- xg GEMM via MFMA bf16x3 split ----------------
__global__ __launch_bounds__(256) void k_xg(
    const unsigned* __restrict__ spec, const float* __restrict__ embxg,
    const short* __restrict__ wxb_hi, const short* __restrict__ wxb_lo,
    float* __restrict__ xg) {
  int nb  = blockIdx.x % XG_NB;
  int mb  = blockIdx.x / XG_NB;
  int fr0 = mb * 64;
  int tid = threadIdx.x;
  int lane = tid & 63;
  int wv   = tid >> 6;

  __shared__ __align__(16) short lsA[2][64 * 40];
  __shared__ __align__(16) short lsB[2][256 * 40];

  f32x4 acc[4][4];
  #pragma unroll
  for (int i = 0; i < 4; ++i)
    #pragma unroll
    for (int j = 0; j < 4; ++j)
      acc[i][j] = (f32x4){0.f, 0.f, 0.f, 0.f};

  int lrow = lane & 15;
  int lk8  = (lane >> 4) * 8;

  for (int ks = 0; ks < XG_KS; ++ks) {
    int k0 = ks * 32;
    {
      int f = tid >> 2, q = tid & 3;
      int fr = fr0 + f;
      short hi[8], lo[8];
      #pragma unroll
      for (int j = 0; j < 8; ++j) {
        int bg = k0 + q * 8 + j;
        float m = 0.f;
        if (fr < NFRAMES && bg <= 512) {
          unsigned pv = spec[(size_t)fr * (FR_STRIDE / 2) + bg];
          float rr = bf2f((unsigned short)(pv & 0xFFFFu));
          float ii = bf2f((unsigned short)(pv >> 16));
          m = sqrtf(rr * rr + ii * ii);
        }
        split_bf16(m, hi[j], lo[j]);
      }
      int off = f * 40 + q * 8;
      *(bf16x8*)&lsA[0][off] = *(bf16x8*)hi;
      *(bf16x8*)&lsA[1][off] = *(bf16x8*)lo;
    }
    {
      const short* gh = wxb_hi + (((size_t)nb * XG_KS + ks) * 256 + tid) * 32;
      const short* gl = wxb_lo + (((size_t)nb * XG_KS + ks) * 256 + tid) * 32;
      int off = tid * 40;
      #pragma unroll
      for (int i = 0; i < 4; ++i) {
        *(bf16x8*)&lsB[0][off + 8 * i] = *(const bf16x8*)(gh + 8 * i);
        *(bf16x8*)&lsB[1][off + 8 * i] = *(const bf16x8*)(gl + 8 * i);
      }
    }
    __syncthreads();
    bf16x8 aH[4], aL[4], bH[4], bL[4];
    #pragma unroll
    for (int mt = 0; mt < 4; ++mt) {
      int off = (16 * mt + lrow) * 40 + lk8;
      aH[mt] = *(const bf16x8*)&lsA[0][off];
      aL[mt] = *(const bf16x8*)&lsA[1][off];
    }
    #pragma unroll
    for (int nt = 0; nt < 4; ++nt) {
      int col = wv * 64 + nt * 16 + lrow;
      int off = col * 40 + lk8;
      bH[nt] = *(const bf16x8*)&lsB[0][off];
      bL[nt] = *(const bf16x8*)&lsB[1][off];
    }
    #pragma unroll
    for (int mt = 0; mt < 4; ++mt)
      #pragma unroll
      for (int nt = 0; nt < 4; ++nt) {
        acc[mt][nt] = __builtin_amdgcn_mfma_f32_16x16x32_bf16(aH[mt], bH[nt], acc[mt][nt], 0, 0, 0);
        acc[mt][nt] = __builtin_amdgcn_mfma_f32_16x16x32_bf16(aH[mt], bL[nt], acc[mt][nt], 0, 0, 0);
        acc[mt][nt] = __builtin_amdgcn_mfma_f32_16x16x32_bf16(aL[mt], bH[nt], acc[mt][nt], 0, 0, 0);
      }
    __syncthreads();
  }

  int ncol0 = nb * 256 + wv * 64;
  #pragma unroll
  for (int mt = 0; mt < 4; ++mt) {
    #pragma unroll
    for (int r = 0; r < 4; ++r) {
      int fr = fr0 + mt * 16 + (lane >> 4) * 4 + r;
      if (fr < NFRAMES) {
        int b = fr / KCF;
        #pragma unroll
        for (int nt = 0; nt < 4; ++nt) {
          int col = ncol0 + nt * 16 + (lane & 15);
          xg[(size_t)fr * GDIM + col] = acc[mt][nt][r] + embxg[(size_t)b * GDIM + col];
        }
      }
    }
  }
}

// ---------------- GRU: 768 threads/block, 1 output column per thread (PROVEN r4/r5) ----------------
__global__ __launch_bounds__(768) void k_gru(
    const float* __restrict__ xg, const float* __restrict__ wh,
    const float* __restrict__ bias, float* __restrict__ hs) {
  int c0 = blockIdx.x * GRU_CT;
  int tid = threadIdx.x;                 // 0..767 == output column (gate*256+unit)
  __shared__ __align__(16) float h[GRU_CT][HDIM];    // 5 KB
  __shared__ float hg[GRU_CT][GDIM];                 // 15 KB
  float* hflat = &h[0][0];
  for (int i = tid; i < GRU_CT * HDIM; i += 768) hflat[i] = 0.f;
  float bcol = bias[tid];
  __syncthreads();
  for (int t = 0; t < NFR; ++t) {
    float acc[GRU_CT];
    #pragma unroll
    for (int c = 0; c < GRU_CT; ++c) acc[c] = bcol;
    const float* wcol = wh + tid;
    #pragma unroll 2
    for (int k = 0; k < HDIM; k += 4) {
      float w0 = wcol[(size_t)(k + 0) * GDIM];
      float w1 = wcol[(size_t)(k + 1) * GDIM];
      float w2 = wcol[(size_t)(k + 2) * GDIM];
      float w3 = wcol[(size_t)(k + 3) * GDIM];
      #pragma unroll
      for (int c = 0; c < GRU_CT; ++c) {
        float4 hv = *(const float4*)&h[c][k];     // broadcast read
        acc[c] += hv.x * w0 + hv.y * w1 + hv.z * w2 + hv.w * w3;
      }
    }
    #pragma unroll
    for (int c = 0; c < GRU_CT; ++c) hg[c][tid] = acc[c];
    __syncthreads();
    // nonlinearity: 1280 (chunk,unit) items over 768 threads
    for (int i = tid; i < GRU_CT * HDIM; i += 768) {
      int c = i >> 8, u = i & 255;
      int cb = c0 + c;
      if (cb < NCHUNKS) {
        const float* xgt = xg + (size_t)(cb * NFR + t) * GDIM;
        float z = 1.f / (1.f + expf(-(xgt[u] + hg[c][u])));
        float r = 1.f / (1.f + expf(-(xgt[u + 256] + hg[c][u + 256])));
        float n = tanhf(xgt[u + 512] + r * hg[c][u + 512]);
        float hn = (1.f - z) * n + z * h[c][u];
        h[c][u] = hn;                    // unique (c,u) per thread: safe in-place
        hs[(size_t)(cb * NFR + t) * HDIM + u] = hn;
      }
    }
    __syncthreads();
  }
}

// ---------------- proj GEMM via MFMA: gb[fr][col] = hs@pw + pb, bf16 output ----------------
__global__ __launch_bounds__(256) void k_proj(
    const float* __restrict__ hs, const short* __restrict__ pwb_hi,
    const short* __restrict__ pwb_lo, const float* __restrict__ pb,
    unsigned short* __restrict__ gb) {
  int nb  = blockIdx.x % PJ_NB;
  int mb  = blockIdx.x / PJ_NB;
  int fr0 = mb * 64;
  int tid = threadIdx.x;
  int lane = tid & 63;
  int wv   = tid >> 6;

  __shared__ __align__(16) short lsA[2][64 * 40];
  __shared__ __align__(16) short lsB[2][256 * 40];

  f32x4 acc[4][4];
  #pragma unroll
  for (int i = 0; i < 4; ++i)
    #pragma unroll
    for (int j = 0; j < 4; ++j)
      acc[i][j] = (f32x4){0.f, 0.f, 0.f, 0.f};

  int lrow = lane & 15;
  int lk8  = (lane >> 4) * 8;

  for (int ks = 0; ks < PJ_KS; ++ks) {
    {
      int f = tid >> 2, q = tid & 3;
      int fr = fr0 + f;
      float v[8];
      if (fr < NFRAMES) {
        const float* src = hs + (size_t)fr * HDIM + ks * 32 + q * 8;
        float4 v0 = *(const float4*)src;
        float4 v1 = *(const float4*)(src + 4);
        v[0]=v0.x; v[1]=v0.y; v[2]=v0.z; v[3]=v0.w;
        v[4]=v1.x; v[5]=v1.y; v[6]=v1.z; v[7]=v1.w;
      } else {
        #pragma unroll
        for (int j = 0; j < 8; ++j) v[j] = 0.f;
      }
      short hi[8], lo[8];
      #pragma unroll
      for (int j = 0; j < 8; ++j) split_bf16(v[j], hi[j], lo[j]);
      int off = f * 40 + q * 8;
      *(bf16x8*)&lsA[0][off] = *(bf16x8*)hi;
      *(bf16x8*)&lsA[1][off] = *(bf16x8*)lo;
    }
    {
      const short* gh = pwb_hi + (((size_t)nb * PJ_KS + ks) * 256 + tid) * 32;
      const short* gl = pwb_lo + (((size_t)nb * PJ_KS + ks) * 256 + tid) * 32;
      int off = tid * 40;
      #pragma unroll
      for (int i = 0; i < 4; ++i) {
        *(bf16x8*)&lsB[0][off + 8 * i] = *(const bf16x8*)(gh + 8 * i);
        *(bf16x8*)&lsB[1][off + 8 * i] = *(const bf16x8*)(gl + 8 * i);
      }
    }
    __syncthreads();
    bf16x8 aH[4], aL[4], bH[4], bL[4];
    #pragma unroll
    for (int mt = 0; mt < 4; ++mt) {
      int off = (16 * mt + lrow) * 40 + lk8;
      aH[mt] = *(const bf16x8*)&lsA[0][off];
      aL[mt] = *(const bf16x8*)&lsA[1][off];
    }
    #pragma unroll
    for (int nt = 0; nt < 4; ++nt) {
      int col = wv * 64 + nt * 16 + lrow;
      int off = col * 40 + lk8;
      bH[nt] = *(const bf16x8*)&lsB[0][off];
      bL[nt] = *(const bf16x8*)&lsB[1][off];
    }
    #pragma unroll
    for (int mt = 0; mt < 4; ++mt)
      #pragma unroll
      for (int nt = 0; nt < 4; ++nt) {
        acc[mt][nt] = __builtin_amdgcn_mfma_f32_16x16x32_bf16(aH[mt], bH[nt], acc[mt][nt], 0, 0, 0);
        acc[mt][nt] = __builtin_amdgcn_mfma_f32_16x16x32_bf16(aH[mt], bL[nt], acc[mt][nt], 0, 0, 0);
        acc[mt][nt] = __builtin_amdgcn_mfma_f32_16x16x32_bf16(aL[mt], bH[nt], acc[mt][nt], 0, 0, 0);
      }
    __syncthreads();
  }

  int ncol0 = nb * 256 + wv * 64;
  float pbv[4];
  int cols[4];
  #pragma unroll
  for (int nt = 0; nt < 4; ++nt) {
    cols[nt] = ncol0 + nt * 16 + (lane & 15);
    pbv[nt] = (cols[nt] < PDIM) ? pb[cols[nt]] : 0.f;
  }
  #pragma unroll
  for (int mt = 0; mt < 4; ++mt) {
    #pragma unroll
    for (int r = 0; r < 4; ++r) {
      int fr = fr0 + mt * 16 + (lane >> 4) * 4 + r;
      if (fr < NFRAMES) {
        #pragma unroll
        for (int nt = 0; nt < 4; ++nt) {
          if (cols[nt] < PDIM)
            gb[(size_t)fr * PDIM + cols[nt]] = f2bf(acc[mt][nt][r] + pbv[nt]);
        }
      }
    }
  }
}

// ---------------- inverse FFT + FiLM modulation + win/wsum scaling; y bf16 into slot ----------------
__global__ void k_istft(unsigned* __restrict__ spec, const unsigned short* __restrict__ gb,
                        const float* __restrict__ win, const float* __restrict__ wsinv,
                        const float* __restrict__ gtwc, const float* __restrict__ gtws) {
  int fr = blockIdx.x;
  int tid = threadIdx.x;
  int t = fr % NFR;
  __shared__ float sre[NFREQ], sim[NFREQ];
  __shared__ float re[NFFT_SZ], im[NFFT_SZ];
  __shared__ float twc[512], tws[512];
  for (int i = tid; i < 512; i += 256) { twc[i] = gtwc[i]; tws[i] = gtws[i]; }
  unsigned* sp = spec + (size_t)fr * (FR_STRIDE / 2);
  const unsigned short* gbrow = gb + (size_t)fr * PDIM;
  for (int f = tid; f < NFREQ; f += 256) {
    unsigned pv = sp[f];
    float r  = bf2f((unsigned short)(pv & 0xFFFFu));
    float iv = bf2f((unsigned short)(pv >> 16));
    float mag = sqrtf(r * r + iv * iv);
    float gamma = bf2f(gbrow[f]);
    float beta  = bf2f(gbrow[NFREQ + f]);
    float mm = gamma * mag + beta;
    float nr, ni;
    if (mag > 0.f) {
      float s = mm / mag;
      nr = r * s; ni = iv * s;
    } else {
      nr = mm; ni = 0.f;   // angle(0)=0
    }
    sre[f] = nr;
    sim[f] = (f == 0 || f == NFREQ - 1) ? 0.f : ni;  // irfft ignores DC/Nyquist imag
  }
  __syncthreads();
  for (int i = tid; i < NFFT_SZ; i += 256) {
    int src = (int)(__brev((unsigned)i) >> 22);
    float r, iv;
    if (src <= 512) { r = sre[src]; iv = sim[src]; }
    else            { r = sre[NFFT_SZ - src]; iv = -sim[NFFT_SZ - src]; }
    re[i] = r; im[i] = iv;
  }
  __syncthreads();
  fft1024(re, im, twc, tws, tid, +1.f);
  // write y as bf16 pairs: 512 uints (1024 shorts) at start of the 513-uint slot
  for (int i2 = tid; i2 < 512; i2 += 256) {
    int ia = 2 * i2, ib = 2 * i2 + 1;
    float ya = re[ia] * (1.0f / (float)NFFT_SZ) * win[ia] * wsinv[t * HOP_SZ + ia];
    float yb = re[ib] * (1.0f / (float)NFFT_SZ) * win[ib] * wsinv[t * HOP_SZ + ib];
    unsigned pa = f2bf(ya);
    unsigned pbp = f2bf(yb);
    sp[i2] = (pbp << 16) | pa;
  }
}

// ---------------- deterministic gather overlap-add (bf16 y) ----------------
__global__ void k_gather(const unsigned short* __restrict__ ybuf, float* __restrict__ out) {
  int gid = blockIdx.x * 256 + threadIdx.x;
  if (gid >= NB * T_LEN) return;
  int b = gid / T_LEN, pos = gid % T_LEN;
  float acc = 0.f;
  int k_hi = min(NK - 1, pos / STRIDESZ);
  int k_lo = (pos >= CHUNKSZ) ? ((pos - (CHUNKSZ - 1) + (STRIDESZ - 1)) / STRIDESZ) : 0;
  for (int k = k_lo; k <= k_hi; ++k) {
    int pc = pos - k * STRIDESZ;
    int t1 = min(NFR - 1, pc >> 8);
    int t0 = (pc > NFFT_SZ - 1) ? ((pc - 768) >> 8) : 0;
    int frbase = (b * NK + k) * NFR;
    for (int tt = t0; tt <= t1; ++tt) {
      acc += bf2f(ybuf[(size_t)(frbase + tt) * FR_STRIDE + (pc - tt * HOP_SZ)]);
    }
  }
  out[gid] = acc;
}

// ---------------- launch ----------------
extern "C" void kernel_launch(void* const* d_in, const int* in_sizes, int n_in,
                              void* d_out, int out_size, void* d_ws, size_t ws_size,
                              hipStream_t stream) {
  const float* audio     = (const float*)d_in[0];
  const float* emb_table = (const float*)d_in[1];
  const float* gru_wx    = (const float*)d_in[2];
  const float* gru_wh    = (const float*)d_in[3];
  const float* gru_b     = (const float*)d_in[4];
  const float* proj_w    = (const float*)d_in[5];
  const float* proj_b    = (const float*)d_in[6];
  const int*   effect_id = (const int*)d_in[7];
  float* out = (float*)d_out;

  // explicit byte-offset layout, every region 256B-aligned; total ~102.8 MB
  char* base = (char*)d_ws;
  size_t off = 0;
  auto alloc = [&](size_t bytes) { char* p = base + off; off = (off + bytes + 255) & ~(size_t)255; return p; };
  unsigned* spec   = (unsigned*)alloc((size_t)NFRAMES * FR_STRIDE * 2);     // 33.5 MB (bf16 pairs)
  float*    xg     = (float*)   alloc((size_t)NFRAMES * GDIM * 4);          // 50.2 MB
  float*    hs     = (float*)   alloc((size_t)NFRAMES * HDIM * 4);          // 16.7 MB
  float*    win    = (float*)   alloc(NFFT_SZ * 4);
  float*    wsinv  = (float*)   alloc(CHUNKSZ * 4);
  float*    twc    = (float*)   alloc(512 * 4);
  float*    tws    = (float*)   alloc(512 * 4);
  float*    embxg  = (float*)   alloc(NB * GDIM * 4);
  short*    wxb_hi = (short*)   alloc((size_t)XG_NB * XG_KS * 256 * 32 * 2);
  short*    wxb_lo = (short*)   alloc((size_t)XG_NB * XG_KS * 256 * 32 * 2);
  short*    pwb_hi = (short*)   alloc((size_t)PJ_NB * PJ_KS * 256 * 32 * 2);
  short*    pwb_lo = (short*)   alloc((size_t)PJ_NB * PJ_KS * 256 * 32 * 2);
  unsigned short* gb = (unsigned short*)xg;            // reuse xg region after k_gru (33.5 < 50.2 MB)

  k_tables <<<1, 256, 0, stream>>>(win, wsinv, twc, tws);
  k_embxg  <<<NB, 256, 0, stream>>>(emb_table, effect_id, gru_wx, embxg);
  k_prep   <<<(XG_NB * XG_KS * 256 + 255) / 256, 256, 0, stream>>>(gru_wx, wxb_hi, wxb_lo);
  k_prep_pw<<<(PJ_NB * PJ_KS * 256 + 255) / 256, 256, 0, stream>>>(proj_w, pwb_hi, pwb_lo);
  k_stft   <<<NFRAMES, 256, 0, stream>>>(audio, win, twc, tws, spec);
  k_xg     <<<256 * XG_NB, 256, 0, stream>>>(spec, embxg, wxb_hi, wxb_lo, xg);
  k_gru    <<<(NCHUNKS + GRU_CT - 1) / GRU_CT, 768, 0, stream>>>(xg, gru_wh, gru_b, hs);
  k_proj   <<<256 * PJ_NB, 256, 0, stream>>>(hs, pwb_hi, pwb_lo, proj_b, gb);
  k_istft  <<<NFRAMES, 256, 0, stream>>>(spec, gb, win, wsinv, twc, tws);
  k_gather <<<(NB * T_LEN + 255) / 256, 256, 0, stream>>>((const unsigned short*)spec, out);
}